// Round 4
// baseline (9678.658 us; speedup 1.0000x reference)
//
#include <hip/hip_runtime.h>
#include <hip/hip_bf16.h>
#include <math.h>

// Problem constants (B,S,L,D,H fixed by the reference)
#define BB 4
#define SS 1024
#define DD 1024
#define NH 16
#define HD 64

using bf16 = __hip_bfloat16;
typedef __bf16 bf16x8 __attribute__((ext_vector_type(8)));
typedef float f32x4 __attribute__((ext_vector_type(4)));

// ---------------------------------------------------------------------------
// Dtype probe: flags[0] = 1 if the float buffers are fp32, 0 if bf16.
// Interpret first 8192 half-words of `tokens` as bf16; fp32-underlying gives
// ~23% insane exponents (>=2^70) from mantissa halves, bf16-underlying ~0.
// ---------------------------------------------------------------------------
__global__ __launch_bounds__(256)
void probe_kernel(const void* __restrict__ tokens, int* __restrict__ flags)
{
    const unsigned short* u = (const unsigned short*)tokens;
    int t = threadIdx.x, bad = 0;
    for (int i = t; i < 8192; i += 256) {
        int e = (u[i] >> 7) & 0xFF;
        if (e >= 0xC5) bad++;          // |x| >= 2^70, NaN or Inf — insane here
    }
    __shared__ int red[256];
    red[t] = bad; __syncthreads();
    for (int s = 128; s > 0; s >>= 1) { if (t < s) red[t] += red[t + s]; __syncthreads(); }
    if (t == 0) flags[0] = (red[0] > 16) ? 1 : 0;
}

// ---------------------------------------------------------------------------
// Convert a float tensor (fp32 or bf16 per flags[0]) into the bf16 arena.
// ---------------------------------------------------------------------------
__global__ __launch_bounds__(256)
void cvt_kernel(const void* __restrict__ src, bf16* __restrict__ dst, int n,
                const int* __restrict__ flags)
{
    int i0 = (blockIdx.x * 256 + threadIdx.x) * 8;
    if (i0 >= n) return;
    if (flags[0]) {
        const float* s = (const float*)src;
#pragma unroll
        for (int j = 0; j < 8; ++j) dst[i0 + j] = __float2bfloat16(s[i0 + j]);
    } else {
        *(bf16x8*)(dst + i0) = *(const bf16x8*)((const bf16*)src + i0);
    }
}

// ---------------------------------------------------------------------------
// Generic MFMA GEMM: C[m,n] = sum_k A[m,k]*W[n,k] + bias[n]  (+ epilogue)
// One 16x16 tile per wave, 4 waves/block. Layouts HW-verified (m89/m91):
// A/B lane holds [lane&15][quad*8+j]; C/D col=lane&15, row=quad*4+reg.
// OUT: 0=bf16. RES: 0 none, 1 bf16. SCALE: *scaleb[row>>10].
// ---------------------------------------------------------------------------
template<int RES, bool SCALE>
__global__ __launch_bounds__(256)
void gemm_kernel(const bf16* __restrict__ A, const bf16* __restrict__ W, int ldw,
                 const bf16* __restrict__ bias, bf16* __restrict__ Cout,
                 const bf16* __restrict__ Res, const float* __restrict__ scaleb,
                 int K, int ldc)
{
    const int wave = threadIdx.x >> 6;
    const int lane = threadIdx.x & 63;
    const int quad = lane >> 4;
    const int l15  = lane & 15;
    const int n0 = blockIdx.x * 16;
    const int m0 = blockIdx.y * 64 + wave * 16;

    const bf16x8* pa = (const bf16x8*)(A + (size_t)(m0 + l15) * K) + quad;
    const bf16x8* pw = (const bf16x8*)(W + (size_t)(n0 + l15) * ldw) + quad;

    f32x4 acc = {0.f, 0.f, 0.f, 0.f};
    const int steps = K >> 5;
#pragma unroll 4
    for (int s = 0; s < steps; ++s) {
        acc = __builtin_amdgcn_mfma_f32_16x16x32_bf16(pa[s * 4], pw[s * 4], acc, 0, 0, 0);
    }

    const int col = n0 + l15;
    const float bs = (float)bias[col];
    const float scl = SCALE ? scaleb[m0 >> 10] : 1.f;
#pragma unroll
    for (int i = 0; i < 4; ++i) {
        int row = m0 + quad * 4 + i;
        float v = acc[i] + bs;
        if (SCALE) v *= scl;
        size_t off = (size_t)row * ldc + col;
        if (RES == 1) v += (float)Res[off];
        Cout[off] = __float2bfloat16(v);
    }
}

template<int RES, bool SCALE>
static void launch_gemm(const bf16* A, const bf16* W, int ldw, const bf16* bias,
                        bf16* C, const bf16* Res, const float* scaleb,
                        int rows, int N, int K, int ldc, hipStream_t st)
{
    dim3 g(N / 16, rows / 64);
    gemm_kernel<RES, SCALE><<<g, 256, 0, st>>>(A, W, ldw, bias, C, Res, scaleb, K, ldc);
}

// ---------------------------------------------------------------------------
// Final down-proj GEMM over a 2048-row chunk: out = ACT@W.T + b + T3 (fp32 res),
// stored to d_out as fp32 or bf16 per flags[0].
// ---------------------------------------------------------------------------
__global__ __launch_bounds__(256)
void down_gemm_kernel(const bf16* __restrict__ ACT, const bf16* __restrict__ W,
                      const bf16* __restrict__ bias, void* __restrict__ out,
                      const float* __restrict__ T3, const int* __restrict__ flags,
                      int row0)
{
    const int wave = threadIdx.x >> 6;
    const int lane = threadIdx.x & 63;
    const int quad = lane >> 4;
    const int l15  = lane & 15;
    const int n0 = blockIdx.x * 16;
    const int m0 = blockIdx.y * 64 + wave * 16;     // chunk-local

    const bf16x8* pa = (const bf16x8*)(ACT + (size_t)(m0 + l15) * 4096) + quad;
    const bf16x8* pw = (const bf16x8*)(W + (size_t)(n0 + l15) * 4096) + quad;

    f32x4 acc = {0.f, 0.f, 0.f, 0.f};
#pragma unroll 4
    for (int s = 0; s < 128; ++s) {
        acc = __builtin_amdgcn_mfma_f32_16x16x32_bf16(pa[s * 4], pw[s * 4], acc, 0, 0, 0);
    }

    const int col = n0 + l15;
    const float bs = (float)bias[col];
    const int f32out = flags[0];
#pragma unroll
    for (int i = 0; i < 4; ++i) {
        size_t row = (size_t)row0 + m0 + quad * 4 + i;
        size_t off = row * 1024 + col;
        float v = acc[i] + bs + T3[off];
        if (f32out) ((float*)out)[off] = v;
        else        ((bf16*)out)[off] = __float2bfloat16(v);
    }
}

// ---------------------------------------------------------------------------
// Gate GEMM: GT = sigmoid(T2 @ Wg[:, :1024].T + UP @ Wg[:, 1024:].T + b)
// ---------------------------------------------------------------------------
__global__ __launch_bounds__(256)
void gate_gemm_kernel(const bf16* __restrict__ A1, const bf16* __restrict__ A2,
                      const bf16* __restrict__ Wg, const bf16* __restrict__ bias,
                      bf16* __restrict__ GT)
{
    const int wave = threadIdx.x >> 6;
    const int lane = threadIdx.x & 63;
    const int quad = lane >> 4;
    const int l15  = lane & 15;
    const int n0 = blockIdx.x * 16;
    const int m0 = blockIdx.y * 64 + wave * 16;

    const bf16x8* pa1 = (const bf16x8*)(A1 + (size_t)(m0 + l15) * 1024) + quad;
    const bf16x8* pa2 = (const bf16x8*)(A2 + (size_t)(m0 + l15) * 1024) + quad;
    const bf16x8* pw1 = (const bf16x8*)(Wg + (size_t)(n0 + l15) * 2048) + quad;
    const bf16x8* pw2 = pw1 + 128;

    f32x4 acc = {0.f, 0.f, 0.f, 0.f};
#pragma unroll 4
    for (int s = 0; s < 32; ++s) {
        acc = __builtin_amdgcn_mfma_f32_16x16x32_bf16(pa1[s * 4], pw1[s * 4], acc, 0, 0, 0);
        acc = __builtin_amdgcn_mfma_f32_16x16x32_bf16(pa2[s * 4], pw2[s * 4], acc, 0, 0, 0);
    }

    const int col = n0 + l15;
    const float bs = (float)bias[col];
#pragma unroll
    for (int i = 0; i < 4; ++i) {
        int row = m0 + quad * 4 + i;
        float v = fminf(fmaxf(acc[i] + bs, -60.f), 60.f);
        GT[(size_t)row * 1024 + col] = __float2bfloat16(1.f / (1.f + __expf(-v)));
    }
}

// ---------------------------------------------------------------------------
// Fused SwiGLU GEMM over a row-chunk:
// ACT[m,n] = silu(Hb@gu_w[n].T + b[n]) * (Hb@gu_w[4096+n].T + b[4096+n])
// ---------------------------------------------------------------------------
__global__ __launch_bounds__(256)
void gu_gemm_kernel(const bf16* __restrict__ Hb, const bf16* __restrict__ Wgu,
                    const bf16* __restrict__ bgu, bf16* __restrict__ ACT)
{
    const int wave = threadIdx.x >> 6;
    const int lane = threadIdx.x & 63;
    const int quad = lane >> 4;
    const int l15  = lane & 15;
    const int n0 = blockIdx.x * 16;
    const int m0 = blockIdx.y * 64 + wave * 16;

    const bf16x8* pa = (const bf16x8*)(Hb + (size_t)(m0 + l15) * 1024) + quad;
    const bf16x8* pg = (const bf16x8*)(Wgu + (size_t)(n0 + l15) * 1024) + quad;
    const bf16x8* pv = (const bf16x8*)(Wgu + (size_t)(4096 + n0 + l15) * 1024) + quad;

    f32x4 accg = {0.f, 0.f, 0.f, 0.f};
    f32x4 accv = {0.f, 0.f, 0.f, 0.f};
#pragma unroll 4
    for (int s = 0; s < 32; ++s) {
        bf16x8 av = pa[s * 4];
        accg = __builtin_amdgcn_mfma_f32_16x16x32_bf16(av, pg[s * 4], accg, 0, 0, 0);
        accv = __builtin_amdgcn_mfma_f32_16x16x32_bf16(av, pv[s * 4], accv, 0, 0, 0);
    }

    const int col = n0 + l15;
    const float bg = (float)bgu[col];
    const float bv = (float)bgu[4096 + col];
#pragma unroll
    for (int i = 0; i < 4; ++i) {
        int row = m0 + quad * 4 + i;
        float g = fminf(fmaxf(accg[i] + bg, -60.f), 60.f);
        float v = accv[i] + bv;
        float s = g / (1.f + __expf(-g));
        ACT[(size_t)row * 4096 + col] = __float2bfloat16(s * v);
    }
}

// ---------------------------------------------------------------------------
// FiLM projection: F[b,0:1024]=1+0.1*tanh(mod@film_w.T+b) ; F[b,1024:2048]=shift
// ---------------------------------------------------------------------------
__global__ __launch_bounds__(256)
void film_kernel(const bf16* __restrict__ mod, const bf16* __restrict__ fw,
                 const bf16* __restrict__ fb, float* __restrict__ F)
{
    int o = blockIdx.x * 256 + threadIdx.x;    // 0..8191
    int b = o >> 11, c = o & 2047;
    const bf16x8* m = (const bf16x8*)(mod + b * DD);
    const bf16x8* w = (const bf16x8*)(fw + (size_t)c * DD);
    float s = (float)fb[c];
    for (int j = 0; j < DD / 8; ++j) {
        bf16x8 mv = m[j], wv = w[j];
#pragma unroll
        for (int e = 0; e < 8; ++e) s += (float)mv[e] * (float)wv[e];
    }
    if (c < 1024) s = 1.f + 0.1f * tanhf(s);
    F[o] = s;
}

// ---------------------------------------------------------------------------
// RMSNorm (optionally + FiLM). One block per row of 1024.
// ---------------------------------------------------------------------------
template<typename TIN, int FILM>
__global__ __launch_bounds__(256)
void rmsnorm_kernel(const TIN* __restrict__ in, const bf16* __restrict__ w,
                    bf16* __restrict__ out, const float* __restrict__ F)
{
    int row = blockIdx.x, t = threadIdx.x, b = row >> 10;
    const TIN* x = in + (size_t)row * DD;
    float v[4];
#pragma unroll
    for (int i = 0; i < 4; ++i) v[i] = (float)x[t * 4 + i];
    float ss = v[0]*v[0] + v[1]*v[1] + v[2]*v[2] + v[3]*v[3];
    __shared__ float red[256];
    red[t] = ss; __syncthreads();
    for (int s = 128; s > 0; s >>= 1) { if (t < s) red[t] += red[t + s]; __syncthreads(); }
    float rn = rsqrtf(red[0] * (1.f / DD) + 1e-6f);
#pragma unroll
    for (int i = 0; i < 4; ++i) {
        int d = t * 4 + i;
        float y = v[i] * rn * (float)w[d];
        if (FILM) y = y * F[b * 2048 + d] + F[b * 2048 + 1024 + d];
        out[(size_t)row * DD + d] = __float2bfloat16(y);
    }
}

// ---------------------------------------------------------------------------
// Mask preprocessing with in-kernel int32-vs-int8 detection.
// valid[b,s] = allpad ? 1 : !mask[b,s];  vr[b] = any(!mask[b,:])
// ---------------------------------------------------------------------------
__global__ __launch_bounds__(256)
void mask_kernel(const void* __restrict__ mask, int* __restrict__ valid,
                 float* __restrict__ vr)
{
    int b = blockIdx.x, t = threadIdx.x;
    const unsigned* mi = (const unsigned*)mask;
    const unsigned char* mb = (const unsigned char*)mask;
    __shared__ int red[256];

    // dtype detect: first 1024 words (4KB — within buffer for both layouts)
    int viol = 0;
    for (int i = t; i < 1024; i += 256) if (mi[i] > 1u) viol++;
    red[t] = viol; __syncthreads();
    for (int s = 128; s > 0; s >>= 1) { if (t < s) red[t] += red[t + s]; __syncthreads(); }
    int isByte = (red[0] > 0);
    __syncthreads();

    int z = 0;
    for (int i = t; i < SS; i += 256) {
        int mv = isByte ? (int)mb[b * SS + i] : (int)mi[b * SS + i];
        z += (mv == 0);
    }
    red[t] = z; __syncthreads();
    for (int s = 128; s > 0; s >>= 1) { if (t < s) red[t] += red[t + s]; __syncthreads(); }
    int nvalid = red[0];
    int allpad = (nvalid == 0);
    for (int i = t; i < SS; i += 256) {
        int mv = isByte ? (int)mb[b * SS + i] : (int)mi[b * SS + i];
        valid[b * SS + i] = allpad ? 1 : (mv ? 0 : 1);
    }
    if (t == 0) vr[b] = (nvalid > 0) ? 1.f : 0.f;
}

// ---------------------------------------------------------------------------
// RoPE in-place on q,k sections of the (4096, 3072) interleaved QKV buffer.
// ---------------------------------------------------------------------------
__global__ __launch_bounds__(256)
void rope_kernel(bf16* __restrict__ qkv)
{
    int row = blockIdx.x;
    int s = row & (SS - 1);
    for (int j = threadIdx.x; j < 1024; j += 256) {
        int sec = j >> 9;
        int p = j & 511;
        int i = p & 31;
        int col = sec * DD + p * 2;
        float fi = __expf(-(float)(2 * i) * 0.14391157f);   // ln(10000)/64
        float ang = (float)s * fi;
        float sn, cs; sincosf(ang, &sn, &cs);
        size_t base = (size_t)row * (3 * DD) + col;
        float e = (float)qkv[base], o = (float)qkv[base + 1];
        qkv[base]     = __float2bfloat16(e * cs - o * sn);
        qkv[base + 1] = __float2bfloat16(e * sn + o * cs);
    }
}

// ---------------------------------------------------------------------------
// Masked attention: q/k/v separate base pointers with common row stride ld.
// One block per (b,h,q).
// ---------------------------------------------------------------------------
__global__ __launch_bounds__(256)
void attn_kernel(const bf16* __restrict__ qp, const bf16* __restrict__ kp,
                 const bf16* __restrict__ vp, int ld,
                 const int* __restrict__ valid, bf16* __restrict__ out)
{
    __shared__ float q[HD];
    __shared__ float sc[SS];
    __shared__ float red[256];
    const int t = threadIdx.x;
    const int sq = blockIdx.x, h = blockIdx.y, b = blockIdx.z;

    if (t < HD) q[t] = (float)qp[((size_t)b * SS + sq) * ld + h * HD + t];
    __syncthreads();

    for (int kk = t; kk < SS; kk += 256) {
        const bf16x8* kr = (const bf16x8*)(kp + ((size_t)b * SS + kk) * ld + h * HD);
        float dot = 0.f;
#pragma unroll
        for (int j = 0; j < 8; ++j) {
            bf16x8 kv = kr[j];
#pragma unroll
            for (int e = 0; e < 8; ++e) dot += q[j * 8 + e] * (float)kv[e];
        }
        sc[kk] = valid[b * SS + kk] ? dot * 0.125f : -3.4e38f;
    }
    __syncthreads();

    float m = -3.4e38f;
    for (int kk = t; kk < SS; kk += 256) m = fmaxf(m, sc[kk]);
    red[t] = m; __syncthreads();
    for (int s = 128; s > 0; s >>= 1) { if (t < s) red[t] = fmaxf(red[t], red[t + s]); __syncthreads(); }
    m = red[0]; __syncthreads();

    float psum = 0.f;
    for (int kk = t; kk < SS; kk += 256) { float e = __expf(sc[kk] - m); sc[kk] = e; psum += e; }
    red[t] = psum; __syncthreads();
    for (int s = 128; s > 0; s >>= 1) { if (t < s) red[t] += red[t + s]; __syncthreads(); }
    float denom = red[0]; __syncthreads();

    const int d = t & 63, g = t >> 6;
    float acc = 0.f;
    for (int kk = g * 256; kk < g * 256 + 256; ++kk)
        acc += sc[kk] * (float)vp[((size_t)b * SS + kk) * ld + h * HD + d];
    red[t] = acc; __syncthreads();
    if (t < HD) {
        float o = red[t] + red[64 + t] + red[128 + t] + red[192 + t];
        out[((size_t)b * SS + sq) * DD + h * HD + t] = __float2bfloat16(o / denom);
    }
}

// ---------------------------------------------------------------------------
// T3(f32) = T2(bf16) + gate(bf16) * update(bf16)
// ---------------------------------------------------------------------------
__global__ __launch_bounds__(256)
void gating_kernel(const bf16* __restrict__ T2, const bf16* __restrict__ GT,
                   const bf16* __restrict__ UPb, float* __restrict__ T3)
{
    size_t idx = (size_t)blockIdx.x * 256 + threadIdx.x;
    T3[idx] = (float)T2[idx] + (float)GT[idx] * (float)UPb[idx];
}

// ---------------------------------------------------------------------------
extern "C" void kernel_launch(void* const* d_in, const int* in_sizes, int n_in,
                              void* d_out, int out_size, void* d_ws, size_t ws_size,
                              hipStream_t stream)
{
    const int M = BB * SS;            // 4096 rows
    const size_t MiB = 1 << 20;

    char* ws = (char*)d_ws;

    // ---- bf16 arena for converted inputs (~64.1 MB) ----
    size_t off = 0;
    auto arena = [&](size_t n) { bf16* p = (bf16*)(ws + off); off += ((n * 2 + 255) & ~(size_t)255); return p; };
    bf16* aTok  = arena(4194304);   // tokens
    bf16* aSeq  = arena(4194304);   // seq_tokens
    bf16* aMod  = arena(4096);
    bf16* aANW  = arena(1024);
    bf16* aQKVW = arena(3145728);
    bf16* aQKVB = arena(3072);
    bf16* aOutW = arena(1048576);
    bf16* aOutB = arena(1024);
    bf16* aFilmW= arena(2097152);
    bf16* aFilmB= arena(2048);
    bf16* aSqN  = arena(1024);
    bf16* aSN   = arena(1024);
    bf16* aMIW  = arena(3145728);
    bf16* aMIB  = arena(3072);
    bf16* aMOW  = arena(1048576);
    bf16* aMOB  = arena(1024);
    bf16* aGW   = arena(2097152);
    bf16* aGB   = arena(1024);
    bf16* aFNW  = arena(1024);
    bf16* aGUW  = arena(8388608);
    bf16* aGUB  = arena(8192);
    bf16* aDW   = arena(4194304);
    bf16* aDB   = arena(1024);

    // ---- pipeline panels (5 x 8 MiB) + smalls ----
    off = (off + MiB - 1) & ~(MiB - 1);
    char* P0 = ws + off;
    char* P1 = P0 + 8 * MiB;
    char* P2 = P0 + 16 * MiB;
    char* P3 = P0 + 24 * MiB;
    char* P4 = P0 + 32 * MiB;
    char* SM = P0 + 40 * MiB;

    bf16* QKV  = (bf16*)P1;          // 24 MiB: P1..P3
    bf16* A    = (bf16*)P0;
    bf16* Q2   = (bf16*)P1;
    bf16* SRC  = (bf16*)P2;
    bf16* CQ   = (bf16*)P3;
    bf16* CK   = (bf16*)P1;
    bf16* CV   = (bf16*)P0;
    bf16* U    = (bf16*)P2;
    bf16* UPb  = (bf16*)P0;
    bf16* GT   = (bf16*)P1;
    float* T3  = (float*)P2;         // 16 MiB: P2..P3
    bf16* Hb   = (bf16*)P4;
    bf16* ACT  = (bf16*)P0;          // 16 MiB chunk: P0..P1
    bf16* X    = (bf16*)d_out;       // d_out >= 8MB in both dtype cases
    bf16* T2   = (bf16*)d_out;

    float* F    = (float*)SM;                  // 32 KB
    int* validP = (int*)(SM + 32 * 1024);
    int* validS = (int*)(SM + 48 * 1024);
    float* vrP  = (float*)(SM + 64 * 1024);
    float* vrS  = (float*)(SM + 64 * 1024 + 256);
    int* flags  = (int*)(SM + 64 * 1024 + 512);

    // 0) dtype probe on tokens
    probe_kernel<<<1, 256, 0, stream>>>(d_in[0], flags);

    // 0b) convert all float tensors to bf16 arena
    struct CvtJob { const void* src; bf16* dst; int n; };
    const CvtJob jobs[23] = {
        {d_in[0],  aTok,  4194304}, {d_in[1],  aSeq,  4194304}, {d_in[2],  aMod,  4096},
        {d_in[3],  aANW,  1024},    {d_in[4],  aQKVW, 3145728}, {d_in[5],  aQKVB, 3072},
        {d_in[6],  aOutW, 1048576}, {d_in[7],  aOutB, 1024},    {d_in[8],  aFilmW,2097152},
        {d_in[9],  aFilmB,2048},    {d_in[10], aSqN,  1024},    {d_in[11], aSN,   1024},
        {d_in[12], aMIW,  3145728}, {d_in[13], aMIB,  3072},    {d_in[14], aMOW,  1048576},
        {d_in[15], aMOB,  1024},    {d_in[16], aGW,   2097152}, {d_in[17], aGB,   1024},
        {d_in[18], aFNW,  1024},    {d_in[19], aGUW,  8388608}, {d_in[20], aGUB,  8192},
        {d_in[21], aDW,   4194304}, {d_in[22], aDB,   1024},
    };
    for (int j = 0; j < 23; ++j) {
        int blocks = (jobs[j].n + 2047) / 2048;
        cvt_kernel<<<blocks, 256, 0, stream>>>(jobs[j].src, jobs[j].dst, jobs[j].n, flags);
    }

    // 1) FiLM + masks
    film_kernel<<<32, 256, 0, stream>>>(aMod, aFilmW, aFilmB, F);
    mask_kernel<<<BB, 256, 0, stream>>>(d_in[23], validP, vrP);
    mask_kernel<<<BB, 256, 0, stream>>>(d_in[24], validS, vrS);

    // 2) X = rmsnorm(tokens)*film_scale + film_shift   (X in d_out)
    rmsnorm_kernel<bf16, 1><<<M, 256, 0, stream>>>(aTok, aANW, X, F);

    // 3) QKV = X @ qkv_w.T + qkv_b
    launch_gemm<0, false>(X, aQKVW, 1024, aQKVB, QKV, nullptr, nullptr,
                          M, 3072, 1024, 3072, stream);

    // 4) RoPE in-place on q,k
    rope_kernel<<<M, 256, 0, stream>>>(QKV);

    // 5) Self-attention -> A
    attn_kernel<<<dim3(SS, NH, BB), 256, 0, stream>>>(QKV, QKV + 1024, QKV + 2048, 3072, validP, A);

    // 6) T2 = tokens + A @ out_w.T + out_b   (into d_out; X dead)
    launch_gemm<1, false>(A, aOutW, 1024, aOutB, T2, aTok, nullptr,
                          M, 1024, 1024, 1024, stream);

    // 7/8) norms for cross-attn
    rmsnorm_kernel<bf16, 0><<<M, 256, 0, stream>>>(T2, aSqN, Q2, nullptr);
    rmsnorm_kernel<bf16, 0><<<M, 256, 0, stream>>>(aSeq, aSN, SRC, nullptr);

    // 9-11) cross projections (CQ first: CK overwrites Q2's panel)
    launch_gemm<0, false>(Q2,  aMIW,           1024, aMIB,        CQ, nullptr, nullptr, M, 1024, 1024, 1024, stream);
    launch_gemm<0, false>(SRC, aMIW + 1048576, 1024, aMIB + 1024, CK, nullptr, nullptr, M, 1024, 1024, 1024, stream);
    launch_gemm<0, false>(SRC, aMIW + 2097152, 1024, aMIB + 2048, CV, nullptr, nullptr, M, 1024, 1024, 1024, stream);

    // 12) cross attention -> U
    attn_kernel<<<dim3(SS, NH, BB), 256, 0, stream>>>(CQ, CK, CV, 1024, validS, U);

    // 13) UPb = (U @ mha_out_w.T + b) * valid_rows
    launch_gemm<0, true>(U, aMOW, 1024, aMOB, UPb, nullptr, vrS,
                         M, 1024, 1024, 1024, stream);

    // 14) GT = sigmoid(T2@Wg[:, :1024].T + UPb@Wg[:, 1024:].T + b)
    gate_gemm_kernel<<<dim3(64, 64), 256, 0, stream>>>(T2, UPb, aGW, aGB, GT);

    // 15) T3 = T2 + GT*UPb  (f32 into P2..P3)
    gating_kernel<<<(M * 1024) / 256, 256, 0, stream>>>(T2, GT, UPb, T3);

    // 16) Hb = rmsnorm(T3)  (into P4; T2 dead)
    rmsnorm_kernel<float, 0><<<M, 256, 0, stream>>>(T3, aFNW, Hb, nullptr);

    // 17/18) FFN in two 2048-row chunks; final store dtype per flags
    for (int c = 0; c < 2; ++c) {
        const int row0 = c * 2048;
        gu_gemm_kernel<<<dim3(256, 32), 256, 0, stream>>>(Hb + (size_t)row0 * 1024, aGUW, aGUB, ACT);
        down_gemm_kernel<<<dim3(64, 32), 256, 0, stream>>>(ACT, aDW, aDB, d_out, T3, flags, row0);
    }
}

// Round 5
// 2750.832 us; speedup vs baseline: 3.5184x; 3.5184x over previous
//
#include <hip/hip_runtime.h>
#include <hip/hip_bf16.h>
#include <math.h>

// Problem constants (B,S,L,D,H fixed by the reference)
#define BB 4
#define SS 1024
#define DD 1024
#define NH 16
#define HD 64

using bf16 = __hip_bfloat16;
typedef __bf16 bf16x8 __attribute__((ext_vector_type(8)));
typedef float f32x4 __attribute__((ext_vector_type(4)));

// ---------------------------------------------------------------------------
// Dtype probe: flags[0] = 1 if the float buffers are fp32, 0 if bf16.
// ---------------------------------------------------------------------------
__global__ __launch_bounds__(256)
void probe_kernel(const void* __restrict__ tokens, int* __restrict__ flags)
{
    const unsigned short* u = (const unsigned short*)tokens;
    int t = threadIdx.x, bad = 0;
    for (int i = t; i < 8192; i += 256) {
        int e = (u[i] >> 7) & 0xFF;
        if (e >= 0xC5) bad++;          // |x| >= 2^70, NaN or Inf — insane here
    }
    __shared__ int red[256];
    red[t] = bad; __syncthreads();
    for (int s = 128; s > 0; s >>= 1) { if (t < s) red[t] += red[t + s]; __syncthreads(); }
    if (t == 0) flags[0] = (red[0] > 16) ? 1 : 0;
}

// ---------------------------------------------------------------------------
// Convert a float tensor (fp32 or bf16 per flags[0]) into the bf16 arena.
// ---------------------------------------------------------------------------
__global__ __launch_bounds__(256)
void cvt_kernel(const void* __restrict__ src, bf16* __restrict__ dst, int n,
                const int* __restrict__ flags)
{
    int i0 = (blockIdx.x * 256 + threadIdx.x) * 8;
    if (i0 >= n) return;
    if (flags[0]) {
        const float* s = (const float*)src;
#pragma unroll
        for (int j = 0; j < 8; ++j) dst[i0 + j] = __float2bfloat16(s[i0 + j]);
    } else {
        *(bf16x8*)(dst + i0) = *(const bf16x8*)((const bf16*)src + i0);
    }
}

// ---------------------------------------------------------------------------
// Generic MFMA GEMM: one 16x16 tile per wave, 4 waves/block.
// A/B lane holds [lane&15][quad*8+j]; C/D col=lane&15, row=quad*4+reg.
// RES: 0 none, 1 bf16. SCALE: *scaleb[row>>10].
// ---------------------------------------------------------------------------
template<int RES, bool SCALE>
__global__ __launch_bounds__(256)
void gemm_kernel(const bf16* __restrict__ A, const bf16* __restrict__ W, int ldw,
                 const bf16* __restrict__ bias, bf16* __restrict__ Cout,
                 const bf16* __restrict__ Res, const float* __restrict__ scaleb,
                 int K, int ldc)
{
    const int wave = threadIdx.x >> 6;
    const int lane = threadIdx.x & 63;
    const int quad = lane >> 4;
    const int l15  = lane & 15;
    const int n0 = blockIdx.x * 16;
    const int m0 = blockIdx.y * 64 + wave * 16;

    const bf16x8* pa = (const bf16x8*)(A + (size_t)(m0 + l15) * K) + quad;
    const bf16x8* pw = (const bf16x8*)(W + (size_t)(n0 + l15) * ldw) + quad;

    f32x4 acc = {0.f, 0.f, 0.f, 0.f};
    const int steps = K >> 5;
#pragma unroll 4
    for (int s = 0; s < steps; ++s) {
        acc = __builtin_amdgcn_mfma_f32_16x16x32_bf16(pa[s * 4], pw[s * 4], acc, 0, 0, 0);
    }

    const int col = n0 + l15;
    const float bs = (float)bias[col];
    const float scl = SCALE ? scaleb[m0 >> 10] : 1.f;
#pragma unroll
    for (int i = 0; i < 4; ++i) {
        int row = m0 + quad * 4 + i;
        float v = acc[i] + bs;
        if (SCALE) v *= scl;
        size_t off = (size_t)row * ldc + col;
        if (RES == 1) v += (float)Res[off];
        Cout[off] = __float2bfloat16(v);
    }
}

template<int RES, bool SCALE>
static void launch_gemm(const bf16* A, const bf16* W, int ldw, const bf16* bias,
                        bf16* C, const bf16* Res, const float* scaleb,
                        int rows, int N, int K, int ldc, hipStream_t st)
{
    dim3 g(N / 16, rows / 64);
    gemm_kernel<RES, SCALE><<<g, 256, 0, st>>>(A, W, ldw, bias, C, Res, scaleb, K, ldc);
}

// ---------------------------------------------------------------------------
// Final down-proj GEMM over a 2048-row chunk: out = ACT@W.T + b + T3 (fp32 res),
// stored to d_out as fp32 or bf16 per flags[0].
// ---------------------------------------------------------------------------
__global__ __launch_bounds__(256)
void down_gemm_kernel(const bf16* __restrict__ ACT, const bf16* __restrict__ W,
                      const bf16* __restrict__ bias, void* __restrict__ out,
                      const float* __restrict__ T3, const int* __restrict__ flags,
                      int row0)
{
    const int wave = threadIdx.x >> 6;
    const int lane = threadIdx.x & 63;
    const int quad = lane >> 4;
    const int l15  = lane & 15;
    const int n0 = blockIdx.x * 16;
    const int m0 = blockIdx.y * 64 + wave * 16;     // chunk-local

    const bf16x8* pa = (const bf16x8*)(ACT + (size_t)(m0 + l15) * 4096) + quad;
    const bf16x8* pw = (const bf16x8*)(W + (size_t)(n0 + l15) * 4096) + quad;

    f32x4 acc = {0.f, 0.f, 0.f, 0.f};
#pragma unroll 4
    for (int s = 0; s < 128; ++s) {
        acc = __builtin_amdgcn_mfma_f32_16x16x32_bf16(pa[s * 4], pw[s * 4], acc, 0, 0, 0);
    }

    const int col = n0 + l15;
    const float bs = (float)bias[col];
    const int f32out = flags[0];
#pragma unroll
    for (int i = 0; i < 4; ++i) {
        size_t row = (size_t)row0 + m0 + quad * 4 + i;
        size_t off = row * 1024 + col;
        float v = acc[i] + bs + T3[off];
        if (f32out) ((float*)out)[off] = v;
        else        ((bf16*)out)[off] = __float2bfloat16(v);
    }
}

// ---------------------------------------------------------------------------
// Gate GEMM: GT = sigmoid(T2 @ Wg[:, :1024].T + UP @ Wg[:, 1024:].T + b)
// ---------------------------------------------------------------------------
__global__ __launch_bounds__(256)
void gate_gemm_kernel(const bf16* __restrict__ A1, const bf16* __restrict__ A2,
                      const bf16* __restrict__ Wg, const bf16* __restrict__ bias,
                      bf16* __restrict__ GT)
{
    const int wave = threadIdx.x >> 6;
    const int lane = threadIdx.x & 63;
    const int quad = lane >> 4;
    const int l15  = lane & 15;
    const int n0 = blockIdx.x * 16;
    const int m0 = blockIdx.y * 64 + wave * 16;

    const bf16x8* pa1 = (const bf16x8*)(A1 + (size_t)(m0 + l15) * 1024) + quad;
    const bf16x8* pa2 = (const bf16x8*)(A2 + (size_t)(m0 + l15) * 1024) + quad;
    const bf16x8* pw1 = (const bf16x8*)(Wg + (size_t)(n0 + l15) * 2048) + quad;
    const bf16x8* pw2 = pw1 + 128;

    f32x4 acc = {0.f, 0.f, 0.f, 0.f};
#pragma unroll 4
    for (int s = 0; s < 32; ++s) {
        acc = __builtin_amdgcn_mfma_f32_16x16x32_bf16(pa1[s * 4], pw1[s * 4], acc, 0, 0, 0);
        acc = __builtin_amdgcn_mfma_f32_16x16x32_bf16(pa2[s * 4], pw2[s * 4], acc, 0, 0, 0);
    }

    const int col = n0 + l15;
    const float bs = (float)bias[col];
#pragma unroll
    for (int i = 0; i < 4; ++i) {
        int row = m0 + quad * 4 + i;
        float v = fminf(fmaxf(acc[i] + bs, -60.f), 60.f);
        GT[(size_t)row * 1024 + col] = __float2bfloat16(1.f / (1.f + __expf(-v)));
    }
}

// ---------------------------------------------------------------------------
// Fused SwiGLU GEMM over a row-chunk.
// ---------------------------------------------------------------------------
__global__ __launch_bounds__(256)
void gu_gemm_kernel(const bf16* __restrict__ Hb, const bf16* __restrict__ Wgu,
                    const bf16* __restrict__ bgu, bf16* __restrict__ ACT)
{
    const int wave = threadIdx.x >> 6;
    const int lane = threadIdx.x & 63;
    const int quad = lane >> 4;
    const int l15  = lane & 15;
    const int n0 = blockIdx.x * 16;
    const int m0 = blockIdx.y * 64 + wave * 16;

    const bf16x8* pa = (const bf16x8*)(Hb + (size_t)(m0 + l15) * 1024) + quad;
    const bf16x8* pg = (const bf16x8*)(Wgu + (size_t)(n0 + l15) * 1024) + quad;
    const bf16x8* pv = (const bf16x8*)(Wgu + (size_t)(4096 + n0 + l15) * 1024) + quad;

    f32x4 accg = {0.f, 0.f, 0.f, 0.f};
    f32x4 accv = {0.f, 0.f, 0.f, 0.f};
#pragma unroll 4
    for (int s = 0; s < 32; ++s) {
        bf16x8 av = pa[s * 4];
        accg = __builtin_amdgcn_mfma_f32_16x16x32_bf16(av, pg[s * 4], accg, 0, 0, 0);
        accv = __builtin_amdgcn_mfma_f32_16x16x32_bf16(av, pv[s * 4], accv, 0, 0, 0);
    }

    const int col = n0 + l15;
    const float bg = (float)bgu[col];
    const float bv = (float)bgu[4096 + col];
#pragma unroll
    for (int i = 0; i < 4; ++i) {
        int row = m0 + quad * 4 + i;
        float g = fminf(fmaxf(accg[i] + bg, -60.f), 60.f);
        float v = accv[i] + bv;
        float s = g / (1.f + __expf(-g));
        ACT[(size_t)row * 4096 + col] = __float2bfloat16(s * v);
    }
}

// ---------------------------------------------------------------------------
// FiLM projection
// ---------------------------------------------------------------------------
__global__ __launch_bounds__(256)
void film_kernel(const bf16* __restrict__ mod, const bf16* __restrict__ fw,
                 const bf16* __restrict__ fb, float* __restrict__ F)
{
    int o = blockIdx.x * 256 + threadIdx.x;    // 0..8191
    int b = o >> 11, c = o & 2047;
    const bf16x8* m = (const bf16x8*)(mod + b * DD);
    const bf16x8* w = (const bf16x8*)(fw + (size_t)c * DD);
    float s = (float)fb[c];
    for (int j = 0; j < DD / 8; ++j) {
        bf16x8 mv = m[j], wv = w[j];
#pragma unroll
        for (int e = 0; e < 8; ++e) s += (float)mv[e] * (float)wv[e];
    }
    if (c < 1024) s = 1.f + 0.1f * tanhf(s);
    F[o] = s;
}

// ---------------------------------------------------------------------------
// RMSNorm (optionally + FiLM). One block per row of 1024.
// ---------------------------------------------------------------------------
template<typename TIN, int FILM>
__global__ __launch_bounds__(256)
void rmsnorm_kernel(const TIN* __restrict__ in, const bf16* __restrict__ w,
                    bf16* __restrict__ out, const float* __restrict__ F)
{
    int row = blockIdx.x, t = threadIdx.x, b = row >> 10;
    const TIN* x = in + (size_t)row * DD;
    float v[4];
#pragma unroll
    for (int i = 0; i < 4; ++i) v[i] = (float)x[t * 4 + i];
    float ss = v[0]*v[0] + v[1]*v[1] + v[2]*v[2] + v[3]*v[3];
    __shared__ float red[256];
    red[t] = ss; __syncthreads();
    for (int s = 128; s > 0; s >>= 1) { if (t < s) red[t] += red[t + s]; __syncthreads(); }
    float rn = rsqrtf(red[0] * (1.f / DD) + 1e-6f);
#pragma unroll
    for (int i = 0; i < 4; ++i) {
        int d = t * 4 + i;
        float y = v[i] * rn * (float)w[d];
        if (FILM) y = y * F[b * 2048 + d] + F[b * 2048 + 1024 + d];
        out[(size_t)row * DD + d] = __float2bfloat16(y);
    }
}

// ---------------------------------------------------------------------------
// Mask preprocessing with in-kernel int32-vs-int8 detection.
// ---------------------------------------------------------------------------
__global__ __launch_bounds__(256)
void mask_kernel(const void* __restrict__ mask, int* __restrict__ valid,
                 float* __restrict__ vr)
{
    int b = blockIdx.x, t = threadIdx.x;
    const unsigned* mi = (const unsigned*)mask;
    const unsigned char* mb = (const unsigned char*)mask;
    __shared__ int red[256];

    int viol = 0;
    for (int i = t; i < 1024; i += 256) if (mi[i] > 1u) viol++;
    red[t] = viol; __syncthreads();
    for (int s = 128; s > 0; s >>= 1) { if (t < s) red[t] += red[t + s]; __syncthreads(); }
    int isByte = (red[0] > 0);
    __syncthreads();

    int z = 0;
    for (int i = t; i < SS; i += 256) {
        int mv = isByte ? (int)mb[b * SS + i] : (int)mi[b * SS + i];
        z += (mv == 0);
    }
    red[t] = z; __syncthreads();
    for (int s = 128; s > 0; s >>= 1) { if (t < s) red[t] += red[t + s]; __syncthreads(); }
    int nvalid = red[0];
    int allpad = (nvalid == 0);
    for (int i = t; i < SS; i += 256) {
        int mv = isByte ? (int)mb[b * SS + i] : (int)mi[b * SS + i];
        valid[b * SS + i] = allpad ? 1 : (mv ? 0 : 1);
    }
    if (t == 0) vr[b] = (nvalid > 0) ? 1.f : 0.f;
}

// ---------------------------------------------------------------------------
// RoPE in-place on q,k sections of the (4096, 3072) interleaved QKV buffer.
// ---------------------------------------------------------------------------
__global__ __launch_bounds__(256)
void rope_kernel(bf16* __restrict__ qkv)
{
    int row = blockIdx.x;
    int s = row & (SS - 1);
    for (int j = threadIdx.x; j < 1024; j += 256) {
        int sec = j >> 9;
        int p = j & 511;
        int i = p & 31;
        int col = sec * DD + p * 2;
        float fi = __expf(-(float)(2 * i) * 0.14391157f);   // ln(10000)/64
        float ang = (float)s * fi;
        float sn, cs; sincosf(ang, &sn, &cs);
        size_t base = (size_t)row * (3 * DD) + col;
        float e = (float)qkv[base], o = (float)qkv[base + 1];
        qkv[base]     = __float2bfloat16(e * cs - o * sn);
        qkv[base + 1] = __float2bfloat16(e * sn + o * cs);
    }
}

// ---------------------------------------------------------------------------
// V transpose: vtg[(b*16+h)*64 + d][k] = V[b*1024+k][h*64+d]. One 64x64 tile
// per block, LDS-staged so both global sides are coalesced.
// ---------------------------------------------------------------------------
__global__ __launch_bounds__(256)
void vtrans_kernel(const bf16* __restrict__ vsrc, int ld, bf16* __restrict__ vtg)
{
    __shared__ __bf16 tile[64][65];
    const int t = threadIdx.x;
    const int k0 = blockIdx.x * 64;
    const int h = blockIdx.y, b = blockIdx.z;
#pragma unroll
    for (int j = 0; j < 2; ++j) {
        int lin = j * 256 + t;
        int r = lin >> 3, c8 = (lin & 7) * 8;
        bf16x8 v = *(const bf16x8*)(vsrc + ((size_t)b * 1024 + k0 + r) * ld + h * 64 + c8);
#pragma unroll
        for (int e = 0; e < 8; ++e) tile[r][c8 + e] = v[e];
    }
    __syncthreads();
#pragma unroll
    for (int j = 0; j < 2; ++j) {
        int lin = j * 256 + t;
        int d = lin >> 3, k8 = (lin & 7) * 8;
        __bf16 o[8];
#pragma unroll
        for (int e = 0; e < 8; ++e) o[e] = tile[k8 + e][d];
        *(bf16x8*)(vtg + ((size_t)(b * 16 + h) * 64 + d) * 1024 + k0 + k8) = *(bf16x8*)o;
    }
}

// ---------------------------------------------------------------------------
// Flash-style MFMA attention. Block = (b, h, 64-query tile), 4 waves x 16 q.
// Per 128-key chunk: stage K[128][72], Vt[64][136] in LDS; QK^T by MFMA;
// online softmax (shfl-xor row reduce); P C-layout -> A-layout via per-wave
// LDS [16][136]; PV by MFMA into 4 O-frags. Mask = additive -1e30 bias.
// ---------------------------------------------------------------------------
__global__ __launch_bounds__(256)
void attn_mfma_kernel(const bf16* __restrict__ qp, const bf16* __restrict__ kp,
                      int ld, const bf16* __restrict__ vtg,
                      const int* __restrict__ valid, bf16* __restrict__ out)
{
    __shared__ __bf16 Kl[128][72];        // pad 72: 16B-aligned rows, 2-way max
    __shared__ __bf16 Vl[64][136];        // pad 136: 16B-aligned rows, 2-way max
    __shared__ __bf16 Pl[4][16][136];
    __shared__ float biasl[1024];

    const int t = threadIdx.x;
    const int wave = t >> 6, lane = t & 63, quad = lane >> 4, l15 = lane & 15;
    const int q0 = blockIdx.x * 64;
    const int h = blockIdx.y, b = blockIdx.z;

    for (int i = t; i < 1024; i += 256)
        biasl[i] = valid[b * 1024 + i] ? 0.f : -1e30f;

    const size_t qrow = (size_t)b * 1024 + q0 + wave * 16 + l15;
    const bf16x8 qf0 = *(const bf16x8*)(qp + qrow * ld + h * 64 + quad * 8);
    const bf16x8 qf1 = *(const bf16x8*)(qp + qrow * ld + h * 64 + 32 + quad * 8);

    f32x4 O[4] = {{0,0,0,0},{0,0,0,0},{0,0,0,0},{0,0,0,0}};
    float mrow[4] = {-1e30f, -1e30f, -1e30f, -1e30f};
    float lrow[4] = {0.f, 0.f, 0.f, 0.f};

    for (int ic = 0; ic < 8; ++ic) {
        const int k0 = ic * 128;
        __syncthreads();
#pragma unroll
        for (int j = 0; j < 4; ++j) {
            int lin = j * 256 + t;
            int r = lin >> 3, c8 = (lin & 7) * 8;
            *(bf16x8*)&Kl[r][c8] =
                *(const bf16x8*)(kp + ((size_t)b * 1024 + k0 + r) * ld + h * 64 + c8);
            int d = lin >> 4, s8 = (lin & 15) * 8;
            *(bf16x8*)&Vl[d][s8] =
                *(const bf16x8*)(vtg + ((size_t)(b * 16 + h) * 64 + d) * 1024 + k0 + s8);
        }
        __syncthreads();

        // S = (QK^T)*scale + bias, 8 key sub-tiles of 16
        float sreg[8][4];
#pragma unroll
        for (int f = 0; f < 8; ++f) {
            bf16x8 kb0 = *(const bf16x8*)&Kl[f * 16 + l15][quad * 8];
            bf16x8 kb1 = *(const bf16x8*)&Kl[f * 16 + l15][32 + quad * 8];
            f32x4 s = {0, 0, 0, 0};
            s = __builtin_amdgcn_mfma_f32_16x16x32_bf16(qf0, kb0, s, 0, 0, 0);
            s = __builtin_amdgcn_mfma_f32_16x16x32_bf16(qf1, kb1, s, 0, 0, 0);
            float bfr = biasl[k0 + f * 16 + l15];
#pragma unroll
            for (int i = 0; i < 4; ++i) sreg[f][i] = s[i] * 0.125f + bfr;
        }

        // online softmax
        float mloc[4] = {-1e30f, -1e30f, -1e30f, -1e30f};
#pragma unroll
        for (int f = 0; f < 8; ++f)
#pragma unroll
            for (int i = 0; i < 4; ++i) mloc[i] = fmaxf(mloc[i], sreg[f][i]);
#pragma unroll
        for (int off = 1; off < 16; off <<= 1)
#pragma unroll
            for (int i = 0; i < 4; ++i)
                mloc[i] = fmaxf(mloc[i], __shfl_xor(mloc[i], off));
        float alpha[4];
#pragma unroll
        for (int i = 0; i < 4; ++i) {
            float mn = fmaxf(mrow[i], mloc[i]);
            alpha[i] = __expf(mrow[i] - mn);
            mrow[i] = mn;
            lrow[i] *= alpha[i];
        }
#pragma unroll
        for (int dt = 0; dt < 4; ++dt)
#pragma unroll
            for (int i = 0; i < 4; ++i) O[dt][i] *= alpha[i];

        float lloc[4] = {0.f, 0.f, 0.f, 0.f};
#pragma unroll
        for (int f = 0; f < 8; ++f)
#pragma unroll
            for (int i = 0; i < 4; ++i) {
                float p = __expf(sreg[f][i] - mrow[i]);
                lloc[i] += p;
                Pl[wave][quad * 4 + i][f * 16 + l15] = (__bf16)p;
            }
#pragma unroll
        for (int off = 1; off < 16; off <<= 1)
#pragma unroll
            for (int i = 0; i < 4; ++i) lloc[i] += __shfl_xor(lloc[i], off);
#pragma unroll
        for (int i = 0; i < 4; ++i) lrow[i] += lloc[i];

        __syncthreads();   // drain P writes (lgkmcnt) before A-frag reads

        // O += P @ V
#pragma unroll
        for (int kc = 0; kc < 4; ++kc) {
            bf16x8 pa = *(const bf16x8*)&Pl[wave][l15][kc * 32 + quad * 8];
#pragma unroll
            for (int dt = 0; dt < 4; ++dt) {
                bf16x8 vb = *(const bf16x8*)&Vl[dt * 16 + l15][kc * 32 + quad * 8];
                O[dt] = __builtin_amdgcn_mfma_f32_16x16x32_bf16(pa, vb, O[dt], 0, 0, 0);
            }
        }
    }

#pragma unroll
    for (int i = 0; i < 4; ++i) {
        float inv = 1.f / lrow[i];
        size_t orow = (size_t)b * 1024 + q0 + wave * 16 + quad * 4 + i;
#pragma unroll
        for (int dt = 0; dt < 4; ++dt)
            out[orow * 1024 + h * 64 + dt * 16 + l15] = __float2bfloat16(O[dt][i] * inv);
    }
}

// ---------------------------------------------------------------------------
// T3(f32) = T2(bf16) + gate(bf16) * update(bf16)
// ---------------------------------------------------------------------------
__global__ __launch_bounds__(256)
void gating_kernel(const bf16* __restrict__ T2, const bf16* __restrict__ GT,
                   const bf16* __restrict__ UPb, float* __restrict__ T3)
{
    size_t idx = (size_t)blockIdx.x * 256 + threadIdx.x;
    T3[idx] = (float)T2[idx] + (float)GT[idx] * (float)UPb[idx];
}

// ---------------------------------------------------------------------------
extern "C" void kernel_launch(void* const* d_in, const int* in_sizes, int n_in,
                              void* d_out, int out_size, void* d_ws, size_t ws_size,
                              hipStream_t stream)
{
    const int M = BB * SS;            // 4096 rows
    const size_t MiB = 1 << 20;

    char* ws = (char*)d_ws;

    // ---- bf16 arena for converted inputs (~64.1 MB) ----
    size_t off = 0;
    auto arena = [&](size_t n) { bf16* p = (bf16*)(ws + off); off += ((n * 2 + 255) & ~(size_t)255); return p; };
    bf16* aTok  = arena(4194304);
    bf16* aSeq  = arena(4194304);
    bf16* aMod  = arena(4096);
    bf16* aANW  = arena(1024);
    bf16* aQKVW = arena(3145728);
    bf16* aQKVB = arena(3072);
    bf16* aOutW = arena(1048576);
    bf16* aOutB = arena(1024);
    bf16* aFilmW= arena(2097152);
    bf16* aFilmB= arena(2048);
    bf16* aSqN  = arena(1024);
    bf16* aSN   = arena(1024);
    bf16* aMIW  = arena(3145728);
    bf16* aMIB  = arena(3072);
    bf16* aMOW  = arena(1048576);
    bf16* aMOB  = arena(1024);
    bf16* aGW   = arena(2097152);
    bf16* aGB   = arena(1024);
    bf16* aFNW  = arena(1024);
    bf16* aGUW  = arena(8388608);
    bf16* aGUB  = arena(8192);
    bf16* aDW   = arena(4194304);
    bf16* aDB   = arena(1024);

    // ---- pipeline panels (5 x 8 MiB) + smalls ----
    off = (off + MiB - 1) & ~(MiB - 1);
    char* P0 = ws + off;
    char* P1 = P0 + 8 * MiB;
    char* P2 = P0 + 16 * MiB;
    char* P3 = P0 + 24 * MiB;
    char* P4 = P0 + 32 * MiB;
    char* SM = P0 + 40 * MiB;

    bf16* QKV  = (bf16*)P1;          // 24 MiB: P1..P3
    bf16* A    = (bf16*)P0;
    bf16* Q2   = (bf16*)P1;
    bf16* SRC  = (bf16*)P2;
    bf16* CQ   = (bf16*)P3;
    bf16* CK   = (bf16*)P1;
    bf16* CV   = (bf16*)P0;
    bf16* U    = (bf16*)P2;
    bf16* UPb  = (bf16*)P0;
    bf16* GT   = (bf16*)P1;
    float* T3  = (float*)P2;         // 16 MiB: P2..P3
    bf16* Hb   = (bf16*)P4;
    bf16* Vtg  = (bf16*)P4;          // V-transpose scratch (8 MiB, dead before Hb)
    bf16* ACT  = (bf16*)P0;          // 16 MiB chunk: P0..P1
    bf16* X    = (bf16*)d_out;
    bf16* T2   = (bf16*)d_out;

    float* F    = (float*)SM;
    int* validP = (int*)(SM + 32 * 1024);
    int* validS = (int*)(SM + 48 * 1024);
    float* vrP  = (float*)(SM + 64 * 1024);
    float* vrS  = (float*)(SM + 64 * 1024 + 256);
    int* flags  = (int*)(SM + 64 * 1024 + 512);

    // 0) dtype probe on tokens
    probe_kernel<<<1, 256, 0, stream>>>(d_in[0], flags);

    // 0b) convert all float tensors to bf16 arena
    struct CvtJob { const void* src; bf16* dst; int n; };
    const CvtJob jobs[23] = {
        {d_in[0],  aTok,  4194304}, {d_in[1],  aSeq,  4194304}, {d_in[2],  aMod,  4096},
        {d_in[3],  aANW,  1024},    {d_in[4],  aQKVW, 3145728}, {d_in[5],  aQKVB, 3072},
        {d_in[6],  aOutW, 1048576}, {d_in[7],  aOutB, 1024},    {d_in[8],  aFilmW,2097152},
        {d_in[9],  aFilmB,2048},    {d_in[10], aSqN,  1024},    {d_in[11], aSN,   1024},
        {d_in[12], aMIW,  3145728}, {d_in[13], aMIB,  3072},    {d_in[14], aMOW,  1048576},
        {d_in[15], aMOB,  1024},    {d_in[16], aGW,   2097152}, {d_in[17], aGB,   1024},
        {d_in[18], aFNW,  1024},    {d_in[19], aGUW,  8388608}, {d_in[20], aGUB,  8192},
        {d_in[21], aDW,   4194304}, {d_in[22], aDB,   1024},
    };
    for (int j = 0; j < 23; ++j) {
        int blocks = (jobs[j].n + 2047) / 2048;
        cvt_kernel<<<blocks, 256, 0, stream>>>(jobs[j].src, jobs[j].dst, jobs[j].n, flags);
    }

    // 1) FiLM + masks
    film_kernel<<<32, 256, 0, stream>>>(aMod, aFilmW, aFilmB, F);
    mask_kernel<<<BB, 256, 0, stream>>>(d_in[23], validP, vrP);
    mask_kernel<<<BB, 256, 0, stream>>>(d_in[24], validS, vrS);

    // 2) X = rmsnorm(tokens)*film_scale + film_shift   (X in d_out)
    rmsnorm_kernel<bf16, 1><<<M, 256, 0, stream>>>(aTok, aANW, X, F);

    // 3) QKV = X @ qkv_w.T + qkv_b
    launch_gemm<0, false>(X, aQKVW, 1024, aQKVB, QKV, nullptr, nullptr,
                          M, 3072, 1024, 3072, stream);

    // 4) RoPE in-place on q,k
    rope_kernel<<<M, 256, 0, stream>>>(QKV);

    // 5) Self-attention (MFMA): V transpose into P4, then flash kernel -> A
    vtrans_kernel<<<dim3(16, 16, 4), 256, 0, stream>>>(QKV + 2048, 3072, Vtg);
    attn_mfma_kernel<<<dim3(16, 16, 4), 256, 0, stream>>>(QKV, QKV + 1024, 3072, Vtg, validP, A);

    // 6) T2 = tokens + A @ out_w.T + out_b   (into d_out; X dead)
    launch_gemm<1, false>(A, aOutW, 1024, aOutB, T2, aTok, nullptr,
                          M, 1024, 1024, 1024, stream);

    // 7/8) norms for cross-attn
    rmsnorm_kernel<bf16, 0><<<M, 256, 0, stream>>>(T2, aSqN, Q2, nullptr);
    rmsnorm_kernel<bf16, 0><<<M, 256, 0, stream>>>(aSeq, aSN, SRC, nullptr);

    // 9-11) cross projections (CQ first: CK overwrites Q2's panel)
    launch_gemm<0, false>(Q2,  aMIW,           1024, aMIB,        CQ, nullptr, nullptr, M, 1024, 1024, 1024, stream);
    launch_gemm<0, false>(SRC, aMIW + 1048576, 1024, aMIB + 1024, CK, nullptr, nullptr, M, 1024, 1024, 1024, stream);
    launch_gemm<0, false>(SRC, aMIW + 2097152, 1024, aMIB + 2048, CV, nullptr, nullptr, M, 1024, 1024, 1024, stream);

    // 12) cross attention (MFMA) -> U
    vtrans_kernel<<<dim3(16, 16, 4), 256, 0, stream>>>(CV, 1024, Vtg);
    attn_mfma_kernel<<<dim3(16, 16, 4), 256, 0, stream>>>(CQ, CK, 1024, Vtg, validS, U);

    // 13) UPb = (U @ mha_out_w.T + b) * valid_rows
    launch_gemm<0, true>(U, aMOW, 1024, aMOB, UPb, nullptr, vrS,
                         M, 1024, 1024, 1024, stream);

    // 14) GT = sigmoid(T2@Wg[:, :1024].T + UPb@Wg[:, 1024:].T + b)
    gate_gemm_kernel<<<dim3(64, 64), 256, 0, stream>>>(T2, UPb, aGW, aGB, GT);

    // 15) T3 = T2 + GT*UPb  (f32 into P2..P3)
    gating_kernel<<<(M * 1024) / 256, 256, 0, stream>>>(T2, GT, UPb, T3);

    // 16) Hb = rmsnorm(T3)  (into P4; Vtg dead)
    rmsnorm_kernel<float, 0><<<M, 256, 0, stream>>>(T3, aFNW, Hb, nullptr);

    // 17/18) FFN in two 2048-row chunks; final store dtype per flags
    for (int c = 0; c < 2; ++c) {
        const int row0 = c * 2048;
        gu_gemm_kernel<<<dim3(256, 32), 256, 0, stream>>>(Hb + (size_t)row0 * 1024, aGUW, aGUB, ACT);
        down_gemm_kernel<<<dim3(64, 32), 256, 0, stream>>>(ACT, aDW, aDB, d_out, T3, flags, row0);
    }
}

// Round 6
// 1130.098 us; speedup vs baseline: 8.5644x; 2.4342x over previous
//
#include <hip/hip_runtime.h>
#include <hip/hip_bf16.h>
#include <math.h>

// Problem constants (B,S,L,D,H fixed by the reference)
#define BB 4
#define SS 1024
#define DD 1024
#define NH 16
#define HD 64

using bf16 = __hip_bfloat16;
typedef __bf16 bf16x8 __attribute__((ext_vector_type(8)));
typedef float f32x4 __attribute__((ext_vector_type(4)));

#define AS3(p) ((__attribute__((address_space(3))) void*)(p))
#define AS1(p) ((const __attribute__((address_space(1))) void*)(p))

// ---------------------------------------------------------------------------
// 128-tile GEMM machinery (m97-style).
// Staging: global_load_lds width=16. LDS layout per 16-row group (1KB):
// [quad][l15][8 elems] — identical to lane order of the load instruction AND
// to the MFMA A/B fragment layout, so ds_read_b128 fragment reads are
// conflict-free (2 lanes/bank) with zero repack.
// ---------------------------------------------------------------------------
__device__ __forceinline__ void stage128(const bf16* __restrict__ g, int ld,
                                         int row0, int k0, __bf16* lds,
                                         int wave, int lane)
{
    const int l15 = lane & 15, q = lane >> 4;
#pragma unroll
    for (int j = 0; j < 2; ++j) {
        int grp = wave * 2 + j;
        const bf16* gp = g + (size_t)(row0 + grp * 16 + l15) * ld + k0 + q * 8;
        __builtin_amdgcn_global_load_lds(AS1(gp), AS3((char*)lds + grp * 1024), 16, 0, 0);
    }
}

__device__ __forceinline__ void stage64(const bf16* __restrict__ g, int ld,
                                        int row0, int k0, __bf16* lds,
                                        int wave, int lane)
{
    const int l15 = lane & 15, q = lane >> 4;
    const bf16* gp = g + (size_t)(row0 + wave * 16 + l15) * ld + k0 + q * 8;
    __builtin_amdgcn_global_load_lds(AS1(gp), AS3((char*)lds + wave * 1024), 16, 0, 0);
}

__device__ __forceinline__ bf16x8 ldsfrag(const __bf16* lds, int grp, int quad, int l15)
{
    return *(const bf16x8*)((const char*)lds + grp * 1024 + quad * 256 + l15 * 16);
}

// ---------------------------------------------------------------------------
// Generic 128x128 GEMM: C[m,n] = A[m,:] . W[n,:] + bias[n] (+ epilogue).
// RES: 0 none, 1 bf16. SCALE: *scaleb[m0>>10] (tiles never cross batch).
// ---------------------------------------------------------------------------
template<int RES, bool SCALE>
__global__ __launch_bounds__(256)
void gemm128_kernel(const bf16* __restrict__ A, const bf16* __restrict__ W, int ldw,
                    const bf16* __restrict__ bias, bf16* __restrict__ Cout,
                    const bf16* __restrict__ Res, const float* __restrict__ scaleb,
                    int K, int ldc)
{
    __shared__ __bf16 As[4096], Bs[4096];
    const int wave = threadIdx.x >> 6, lane = threadIdx.x & 63;
    const int quad = lane >> 4, l15 = lane & 15;
    const int n0 = blockIdx.x * 128, m0 = blockIdx.y * 128;
    const int mg0 = (wave >> 1) * 4, ng0 = (wave & 1) * 4;

    f32x4 acc[4][4] = {};
    for (int kt = 0; kt < K; kt += 32) {
        __syncthreads();
        stage128(A, K, m0, kt, As, wave, lane);
        stage128(W, ldw, n0, kt, Bs, wave, lane);
        __syncthreads();
        bf16x8 af[4], bfv[4];
#pragma unroll
        for (int i = 0; i < 4; ++i) af[i] = ldsfrag(As, mg0 + i, quad, l15);
#pragma unroll
        for (int j = 0; j < 4; ++j) bfv[j] = ldsfrag(Bs, ng0 + j, quad, l15);
#pragma unroll
        for (int i = 0; i < 4; ++i)
#pragma unroll
            for (int j = 0; j < 4; ++j)
                acc[i][j] = __builtin_amdgcn_mfma_f32_16x16x32_bf16(af[i], bfv[j], acc[i][j], 0, 0, 0);
    }

    const float scl = SCALE ? scaleb[m0 >> 10] : 1.f;
#pragma unroll
    for (int i = 0; i < 4; ++i) {
#pragma unroll
        for (int j = 0; j < 4; ++j) {
            const int col = n0 + (ng0 + j) * 16 + l15;
            const float bs = (float)bias[col];
#pragma unroll
            for (int r = 0; r < 4; ++r) {
                int row = m0 + (mg0 + i) * 16 + quad * 4 + r;
                float v = acc[i][j][r] + bs;
                if (SCALE) v *= scl;
                size_t off = (size_t)row * ldc + col;
                if (RES == 1) v += (float)Res[off];
                Cout[off] = __float2bfloat16(v);
            }
        }
    }
}

// ---------------------------------------------------------------------------
// Gate GEMM (128-tile): GT = sigmoid(A1@Wg[:, :1024].T + A2@Wg[:, 1024:].T + b)
// K phased: kt<32 -> A1 with W cols 0..1023, kt>=32 -> A2 with cols 1024..2047.
// ---------------------------------------------------------------------------
__global__ __launch_bounds__(256)
void gate128_kernel(const bf16* __restrict__ A1, const bf16* __restrict__ A2,
                    const bf16* __restrict__ Wg, const bf16* __restrict__ bias,
                    bf16* __restrict__ GT)
{
    __shared__ __bf16 As[4096], Bs[4096];
    const int wave = threadIdx.x >> 6, lane = threadIdx.x & 63;
    const int quad = lane >> 4, l15 = lane & 15;
    const int n0 = blockIdx.x * 128, m0 = blockIdx.y * 128;
    const int mg0 = (wave >> 1) * 4, ng0 = (wave & 1) * 4;

    f32x4 acc[4][4] = {};
    for (int kt = 0; kt < 64; ++kt) {
        const bf16* Asrc = (kt < 32) ? A1 : A2;
        __syncthreads();
        stage128(Asrc, 1024, m0, (kt & 31) * 32, As, wave, lane);
        stage128(Wg, 2048, n0, kt * 32, Bs, wave, lane);
        __syncthreads();
        bf16x8 af[4], bfv[4];
#pragma unroll
        for (int i = 0; i < 4; ++i) af[i] = ldsfrag(As, mg0 + i, quad, l15);
#pragma unroll
        for (int j = 0; j < 4; ++j) bfv[j] = ldsfrag(Bs, ng0 + j, quad, l15);
#pragma unroll
        for (int i = 0; i < 4; ++i)
#pragma unroll
            for (int j = 0; j < 4; ++j)
                acc[i][j] = __builtin_amdgcn_mfma_f32_16x16x32_bf16(af[i], bfv[j], acc[i][j], 0, 0, 0);
    }

#pragma unroll
    for (int i = 0; i < 4; ++i)
#pragma unroll
        for (int j = 0; j < 4; ++j) {
            const int col = n0 + (ng0 + j) * 16 + l15;
            const float bs = (float)bias[col];
#pragma unroll
            for (int r = 0; r < 4; ++r) {
                int row = m0 + (mg0 + i) * 16 + quad * 4 + r;
                float v = fminf(fmaxf(acc[i][j][r] + bs, -60.f), 60.f);
                GT[(size_t)row * 1024 + col] = __float2bfloat16(1.f / (1.f + __expf(-v)));
            }
        }
}

// ---------------------------------------------------------------------------
// Fused SwiGLU GEMM (128 rows x 64 cols-per-half):
// ACT[m,n] = silu(Hb@gu_w[n].T+b[n]) * (Hb@gu_w[4096+n].T+b[4096+n])
// ---------------------------------------------------------------------------
__global__ __launch_bounds__(256)
void gu128_kernel(const bf16* __restrict__ Hb, const bf16* __restrict__ Wgu,
                  const bf16* __restrict__ bgu, bf16* __restrict__ ACT)
{
    __shared__ __bf16 As[4096], Bg[2048], Bv[2048];
    const int wave = threadIdx.x >> 6, lane = threadIdx.x & 63;
    const int quad = lane >> 4, l15 = lane & 15;
    const int n0 = blockIdx.x * 64, m0 = blockIdx.y * 128;
    const int mg0 = (wave >> 1) * 4, ng0 = (wave & 1) * 2;
    const bf16* WguV = Wgu + (size_t)4096 * 1024;

    f32x4 ag[4][2] = {}, av[4][2] = {};
    for (int kt = 0; kt < 1024; kt += 32) {
        __syncthreads();
        stage128(Hb, 1024, m0, kt, As, wave, lane);
        stage64(Wgu,  1024, n0, kt, Bg, wave, lane);
        stage64(WguV, 1024, n0, kt, Bv, wave, lane);
        __syncthreads();
        bf16x8 af[4], bgf[2], bvf[2];
#pragma unroll
        for (int i = 0; i < 4; ++i) af[i] = ldsfrag(As, mg0 + i, quad, l15);
#pragma unroll
        for (int j = 0; j < 2; ++j) {
            bgf[j] = ldsfrag(Bg, ng0 + j, quad, l15);
            bvf[j] = ldsfrag(Bv, ng0 + j, quad, l15);
        }
#pragma unroll
        for (int i = 0; i < 4; ++i)
#pragma unroll
            for (int j = 0; j < 2; ++j) {
                ag[i][j] = __builtin_amdgcn_mfma_f32_16x16x32_bf16(af[i], bgf[j], ag[i][j], 0, 0, 0);
                av[i][j] = __builtin_amdgcn_mfma_f32_16x16x32_bf16(af[i], bvf[j], av[i][j], 0, 0, 0);
            }
    }

#pragma unroll
    for (int i = 0; i < 4; ++i)
#pragma unroll
        for (int j = 0; j < 2; ++j) {
            const int col = n0 + (ng0 + j) * 16 + l15;
            const float bg = (float)bgu[col];
            const float bv = (float)bgu[4096 + col];
#pragma unroll
            for (int r = 0; r < 4; ++r) {
                int row = m0 + (mg0 + i) * 16 + quad * 4 + r;
                float g = fminf(fmaxf(ag[i][j][r] + bg, -60.f), 60.f);
                float v = av[i][j][r] + bv;
                float s = g / (1.f + __expf(-g));
                ACT[(size_t)row * 4096 + col] = __float2bfloat16(s * v);
            }
        }
}

// ---------------------------------------------------------------------------
// Down-proj GEMM (128-tile) over a 2048-row chunk: out = ACT@W.T + b + T3(f32),
// stored fp32 or bf16 per flags[0].
// ---------------------------------------------------------------------------
__global__ __launch_bounds__(256)
void down128_kernel(const bf16* __restrict__ ACT, const bf16* __restrict__ W,
                    const bf16* __restrict__ bias, void* __restrict__ out,
                    const float* __restrict__ T3, const int* __restrict__ flags,
                    int row0)
{
    __shared__ __bf16 As[4096], Bs[4096];
    const int wave = threadIdx.x >> 6, lane = threadIdx.x & 63;
    const int quad = lane >> 4, l15 = lane & 15;
    const int n0 = blockIdx.x * 128, m0 = blockIdx.y * 128;
    const int mg0 = (wave >> 1) * 4, ng0 = (wave & 1) * 4;

    f32x4 acc[4][4] = {};
    for (int kt = 0; kt < 4096; kt += 32) {
        __syncthreads();
        stage128(ACT, 4096, m0, kt, As, wave, lane);
        stage128(W, 4096, n0, kt, Bs, wave, lane);
        __syncthreads();
        bf16x8 af[4], bfv[4];
#pragma unroll
        for (int i = 0; i < 4; ++i) af[i] = ldsfrag(As, mg0 + i, quad, l15);
#pragma unroll
        for (int j = 0; j < 4; ++j) bfv[j] = ldsfrag(Bs, ng0 + j, quad, l15);
#pragma unroll
        for (int i = 0; i < 4; ++i)
#pragma unroll
            for (int j = 0; j < 4; ++j)
                acc[i][j] = __builtin_amdgcn_mfma_f32_16x16x32_bf16(af[i], bfv[j], acc[i][j], 0, 0, 0);
    }

    const int f32out = flags[0];
#pragma unroll
    for (int i = 0; i < 4; ++i)
#pragma unroll
        for (int j = 0; j < 4; ++j) {
            const int col = n0 + (ng0 + j) * 16 + l15;
            const float bs = (float)bias[col];
#pragma unroll
            for (int r = 0; r < 4; ++r) {
                size_t row = (size_t)row0 + m0 + (mg0 + i) * 16 + quad * 4 + r;
                size_t off = row * 1024 + col;
                float v = acc[i][j][r] + bs + T3[off];
                if (f32out) ((float*)out)[off] = v;
                else        ((bf16*)out)[off] = __float2bfloat16(v);
            }
        }
}

// ---------------------------------------------------------------------------
// Dtype probe: flags[0] = 1 if the float buffers are fp32, 0 if bf16.
// ---------------------------------------------------------------------------
__global__ __launch_bounds__(256)
void probe_kernel(const void* __restrict__ tokens, int* __restrict__ flags)
{
    const unsigned short* u = (const unsigned short*)tokens;
    int t = threadIdx.x, bad = 0;
    for (int i = t; i < 8192; i += 256) {
        int e = (u[i] >> 7) & 0xFF;
        if (e >= 0xC5) bad++;
    }
    __shared__ int red[256];
    red[t] = bad; __syncthreads();
    for (int s = 128; s > 0; s >>= 1) { if (t < s) red[t] += red[t + s]; __syncthreads(); }
    if (t == 0) flags[0] = (red[0] > 16) ? 1 : 0;
}

// ---------------------------------------------------------------------------
// Convert a float tensor (fp32 or bf16 per flags[0]) into the bf16 arena.
// ---------------------------------------------------------------------------
__global__ __launch_bounds__(256)
void cvt_kernel(const void* __restrict__ src, bf16* __restrict__ dst, int n,
                const int* __restrict__ flags)
{
    int i0 = (blockIdx.x * 256 + threadIdx.x) * 8;
    if (i0 >= n) return;
    if (flags[0]) {
        const float* s = (const float*)src;
#pragma unroll
        for (int j = 0; j < 8; ++j) dst[i0 + j] = __float2bfloat16(s[i0 + j]);
    } else {
        *(bf16x8*)(dst + i0) = *(const bf16x8*)((const bf16*)src + i0);
    }
}

// ---------------------------------------------------------------------------
// FiLM projection
// ---------------------------------------------------------------------------
__global__ __launch_bounds__(256)
void film_kernel(const bf16* __restrict__ mod, const bf16* __restrict__ fw,
                 const bf16* __restrict__ fb, float* __restrict__ F)
{
    int o = blockIdx.x * 256 + threadIdx.x;    // 0..8191
    int b = o >> 11, c = o & 2047;
    const bf16x8* m = (const bf16x8*)(mod + b * DD);
    const bf16x8* w = (const bf16x8*)(fw + (size_t)c * DD);
    float s = (float)fb[c];
    for (int j = 0; j < DD / 8; ++j) {
        bf16x8 mv = m[j], wv = w[j];
#pragma unroll
        for (int e = 0; e < 8; ++e) s += (float)mv[e] * (float)wv[e];
    }
    if (c < 1024) s = 1.f + 0.1f * tanhf(s);
    F[o] = s;
}

// ---------------------------------------------------------------------------
// RMSNorm (optionally + FiLM). One block per row of 1024.
// ---------------------------------------------------------------------------
template<typename TIN, int FILM>
__global__ __launch_bounds__(256)
void rmsnorm_kernel(const TIN* __restrict__ in, const bf16* __restrict__ w,
                    bf16* __restrict__ out, const float* __restrict__ F)
{
    int row = blockIdx.x, t = threadIdx.x, b = row >> 10;
    const TIN* x = in + (size_t)row * DD;
    float v[4];
#pragma unroll
    for (int i = 0; i < 4; ++i) v[i] = (float)x[t * 4 + i];
    float ss = v[0]*v[0] + v[1]*v[1] + v[2]*v[2] + v[3]*v[3];
    __shared__ float red[256];
    red[t] = ss; __syncthreads();
    for (int s = 128; s > 0; s >>= 1) { if (t < s) red[t] += red[t + s]; __syncthreads(); }
    float rn = rsqrtf(red[0] * (1.f / DD) + 1e-6f);
#pragma unroll
    for (int i = 0; i < 4; ++i) {
        int d = t * 4 + i;
        float y = v[i] * rn * (float)w[d];
        if (FILM) y = y * F[b * 2048 + d] + F[b * 2048 + 1024 + d];
        out[(size_t)row * DD + d] = __float2bfloat16(y);
    }
}

// ---------------------------------------------------------------------------
// Mask preprocessing with in-kernel int32-vs-int8 detection.
// ---------------------------------------------------------------------------
__global__ __launch_bounds__(256)
void mask_kernel(const void* __restrict__ mask, int* __restrict__ valid,
                 float* __restrict__ vr)
{
    int b = blockIdx.x, t = threadIdx.x;
    const unsigned* mi = (const unsigned*)mask;
    const unsigned char* mb = (const unsigned char*)mask;
    __shared__ int red[256];

    int viol = 0;
    for (int i = t; i < 1024; i += 256) if (mi[i] > 1u) viol++;
    red[t] = viol; __syncthreads();
    for (int s = 128; s > 0; s >>= 1) { if (t < s) red[t] += red[t + s]; __syncthreads(); }
    int isByte = (red[0] > 0);
    __syncthreads();

    int z = 0;
    for (int i = t; i < SS; i += 256) {
        int mv = isByte ? (int)mb[b * SS + i] : (int)mi[b * SS + i];
        z += (mv == 0);
    }
    red[t] = z; __syncthreads();
    for (int s = 128; s > 0; s >>= 1) { if (t < s) red[t] += red[t + s]; __syncthreads(); }
    int nvalid = red[0];
    int allpad = (nvalid == 0);
    for (int i = t; i < SS; i += 256) {
        int mv = isByte ? (int)mb[b * SS + i] : (int)mi[b * SS + i];
        valid[b * SS + i] = allpad ? 1 : (mv ? 0 : 1);
    }
    if (t == 0) vr[b] = (nvalid > 0) ? 1.f : 0.f;
}

// ---------------------------------------------------------------------------
// RoPE in-place on q,k sections of the (4096, 3072) interleaved QKV buffer.
// ---------------------------------------------------------------------------
__global__ __launch_bounds__(256)
void rope_kernel(bf16* __restrict__ qkv)
{
    int row = blockIdx.x;
    int s = row & (SS - 1);
    for (int j = threadIdx.x; j < 1024; j += 256) {
        int sec = j >> 9;
        int p = j & 511;
        int i = p & 31;
        int col = sec * DD + p * 2;
        float fi = __expf(-(float)(2 * i) * 0.14391157f);   // ln(10000)/64
        float ang = (float)s * fi;
        float sn, cs; sincosf(ang, &sn, &cs);
        size_t base = (size_t)row * (3 * DD) + col;
        float e = (float)qkv[base], o = (float)qkv[base + 1];
        qkv[base]     = __float2bfloat16(e * cs - o * sn);
        qkv[base + 1] = __float2bfloat16(e * sn + o * cs);
    }
}

// ---------------------------------------------------------------------------
// V transpose: vtg[(b*16+h)*64 + d][k] = V[b*1024+k][h*64+d].
// ---------------------------------------------------------------------------
__global__ __launch_bounds__(256)
void vtrans_kernel(const bf16* __restrict__ vsrc, int ld, bf16* __restrict__ vtg)
{
    __shared__ __bf16 tile[64][65];
    const int t = threadIdx.x;
    const int k0 = blockIdx.x * 64;
    const int h = blockIdx.y, b = blockIdx.z;
#pragma unroll
    for (int j = 0; j < 2; ++j) {
        int lin = j * 256 + t;
        int r = lin >> 3, c8 = (lin & 7) * 8;
        bf16x8 v = *(const bf16x8*)(vsrc + ((size_t)b * 1024 + k0 + r) * ld + h * 64 + c8);
#pragma unroll
        for (int e = 0; e < 8; ++e) tile[r][c8 + e] = v[e];
    }
    __syncthreads();
#pragma unroll
    for (int j = 0; j < 2; ++j) {
        int lin = j * 256 + t;
        int d = lin >> 3, k8 = (lin & 7) * 8;
        __bf16 o[8];
#pragma unroll
        for (int e = 0; e < 8; ++e) o[e] = tile[k8 + e][d];
        *(bf16x8*)(vtg + ((size_t)(b * 16 + h) * 64 + d) * 1024 + k0 + k8) = *(bf16x8*)o;
    }
}

// ---------------------------------------------------------------------------
// Flash-style MFMA attention (unchanged from round 5).
// ---------------------------------------------------------------------------
__global__ __launch_bounds__(256)
void attn_mfma_kernel(const bf16* __restrict__ qp, const bf16* __restrict__ kp,
                      int ld, const bf16* __restrict__ vtg,
                      const int* __restrict__ valid, bf16* __restrict__ out)
{
    __shared__ __bf16 Kl[128][72];
    __shared__ __bf16 Vl[64][136];
    __shared__ __bf16 Pl[4][16][136];
    __shared__ float biasl[1024];

    const int t = threadIdx.x;
    const int wave = t >> 6, lane = t & 63, quad = lane >> 4, l15 = lane & 15;
    const int q0 = blockIdx.x * 64;
    const int h = blockIdx.y, b = blockIdx.z;

    for (int i = t; i < 1024; i += 256)
        biasl[i] = valid[b * 1024 + i] ? 0.f : -1e30f;

    const size_t qrow = (size_t)b * 1024 + q0 + wave * 16 + l15;
    const bf16x8 qf0 = *(const bf16x8*)(qp + qrow * ld + h * 64 + quad * 8);
    const bf16x8 qf1 = *(const bf16x8*)(qp + qrow * ld + h * 64 + 32 + quad * 8);

    f32x4 O[4] = {{0,0,0,0},{0,0,0,0},{0,0,0,0},{0,0,0,0}};
    float mrow[4] = {-1e30f, -1e30f, -1e30f, -1e30f};
    float lrow[4] = {0.f, 0.f, 0.f, 0.f};

    for (int ic = 0; ic < 8; ++ic) {
        const int k0 = ic * 128;
        __syncthreads();
#pragma unroll
        for (int j = 0; j < 4; ++j) {
            int lin = j * 256 + t;
            int r = lin >> 3, c8 = (lin & 7) * 8;
            *(bf16x8*)&Kl[r][c8] =
                *(const bf16x8*)(kp + ((size_t)b * 1024 + k0 + r) * ld + h * 64 + c8);
            int d = lin >> 4, s8 = (lin & 15) * 8;
            *(bf16x8*)&Vl[d][s8] =
                *(const bf16x8*)(vtg + ((size_t)(b * 16 + h) * 64 + d) * 1024 + k0 + s8);
        }
        __syncthreads();

        float sreg[8][4];
#pragma unroll
        for (int f = 0; f < 8; ++f) {
            bf16x8 kb0 = *(const bf16x8*)&Kl[f * 16 + l15][quad * 8];
            bf16x8 kb1 = *(const bf16x8*)&Kl[f * 16 + l15][32 + quad * 8];
            f32x4 s = {0, 0, 0, 0};
            s = __builtin_amdgcn_mfma_f32_16x16x32_bf16(qf0, kb0, s, 0, 0, 0);
            s = __builtin_amdgcn_mfma_f32_16x16x32_bf16(qf1, kb1, s, 0, 0, 0);
            float bfr = biasl[k0 + f * 16 + l15];
#pragma unroll
            for (int i = 0; i < 4; ++i) sreg[f][i] = s[i] * 0.125f + bfr;
        }

        float mloc[4] = {-1e30f, -1e30f, -1e30f, -1e30f};
#pragma unroll
        for (int f = 0; f < 8; ++f)
#pragma unroll
            for (int i = 0; i < 4; ++i) mloc[i] = fmaxf(mloc[i], sreg[f][i]);
#pragma unroll
        for (int off = 1; off < 16; off <<= 1)
#pragma unroll
            for (int i = 0; i < 4; ++i)
                mloc[i] = fmaxf(mloc[i], __shfl_xor(mloc[i], off));
        float alpha[4];
#pragma unroll
        for (int i = 0; i < 4; ++i) {
            float mn = fmaxf(mrow[i], mloc[i]);
            alpha[i] = __expf(mrow[i] - mn);
            mrow[i] = mn;
            lrow[i] *= alpha[i];
        }
#pragma unroll
        for (int dt = 0; dt < 4; ++dt)
#pragma unroll
            for (int i = 0; i < 4; ++i) O[dt][i] *= alpha[i];

        float lloc[4] = {0.f, 0.f, 0.f, 0.f};
#pragma unroll
        for (int f = 0; f < 8; ++f)
#pragma unroll
            for (int i = 0; i < 4; ++i) {
                float p = __expf(sreg[f][i] - mrow[i]);
                lloc[i] += p;
                Pl[wave][quad * 4 + i][f * 16 + l15] = (__bf16)p;
            }
#pragma unroll
        for (int off = 1; off < 16; off <<= 1)
#pragma unroll
            for (int i = 0; i < 4; ++i) lloc[i] += __shfl_xor(lloc[i], off);
#pragma unroll
        for (int i = 0; i < 4; ++i) lrow[i] += lloc[i];

        __syncthreads();

#pragma unroll
        for (int kc = 0; kc < 4; ++kc) {
            bf16x8 pa = *(const bf16x8*)&Pl[wave][l15][kc * 32 + quad * 8];
#pragma unroll
            for (int dt = 0; dt < 4; ++dt) {
                bf16x8 vb = *(const bf16x8*)&Vl[dt * 16 + l15][kc * 32 + quad * 8];
                O[dt] = __builtin_amdgcn_mfma_f32_16x16x32_bf16(pa, vb, O[dt], 0, 0, 0);
            }
        }
    }

#pragma unroll
    for (int i = 0; i < 4; ++i) {
        float inv = 1.f / lrow[i];
        size_t orow = (size_t)b * 1024 + q0 + wave * 16 + quad * 4 + i;
#pragma unroll
        for (int dt = 0; dt < 4; ++dt)
            out[orow * 1024 + h * 64 + dt * 16 + l15] = __float2bfloat16(O[dt][i] * inv);
    }
}

// ---------------------------------------------------------------------------
// T3(f32) = T2(bf16) + gate(bf16) * update(bf16)
// ---------------------------------------------------------------------------
__global__ __launch_bounds__(256)
void gating_kernel(const bf16* __restrict__ T2, const bf16* __restrict__ GT,
                   const bf16* __restrict__ UPb, float* __restrict__ T3)
{
    size_t idx = (size_t)blockIdx.x * 256 + threadIdx.x;
    T3[idx] = (float)T2[idx] + (float)GT[idx] * (float)UPb[idx];
}

// ---------------------------------------------------------------------------
extern "C" void kernel_launch(void* const* d_in, const int* in_sizes, int n_in,
                              void* d_out, int out_size, void* d_ws, size_t ws_size,
                              hipStream_t stream)
{
    const int M = BB * SS;            // 4096 rows
    const size_t MiB = 1 << 20;

    char* ws = (char*)d_ws;

    // ---- bf16 arena for converted inputs (~64.1 MB) ----
    size_t off = 0;
    auto arena = [&](size_t n) { bf16* p = (bf16*)(ws + off); off += ((n * 2 + 255) & ~(size_t)255); return p; };
    bf16* aTok  = arena(4194304);
    bf16* aSeq  = arena(4194304);
    bf16* aMod  = arena(4096);
    bf16* aANW  = arena(1024);
    bf16* aQKVW = arena(3145728);
    bf16* aQKVB = arena(3072);
    bf16* aOutW = arena(1048576);
    bf16* aOutB = arena(1024);
    bf16* aFilmW= arena(2097152);
    bf16* aFilmB= arena(2048);
    bf16* aSqN  = arena(1024);
    bf16* aSN   = arena(1024);
    bf16* aMIW  = arena(3145728);
    bf16* aMIB  = arena(3072);
    bf16* aMOW  = arena(1048576);
    bf16* aMOB  = arena(1024);
    bf16* aGW   = arena(2097152);
    bf16* aGB   = arena(1024);
    bf16* aFNW  = arena(1024);
    bf16* aGUW  = arena(8388608);
    bf16* aGUB  = arena(8192);
    bf16* aDW   = arena(4194304);
    bf16* aDB   = arena(1024);

    // ---- pipeline panels (5 x 8 MiB) + smalls ----
    off = (off + MiB - 1) & ~(MiB - 1);
    char* P0 = ws + off;
    char* P1 = P0 + 8 * MiB;
    char* P2 = P0 + 16 * MiB;
    char* P3 = P0 + 24 * MiB;
    char* P4 = P0 + 32 * MiB;
    char* SM = P0 + 40 * MiB;

    bf16* QKV  = (bf16*)P1;          // 24 MiB: P1..P3
    bf16* A    = (bf16*)P0;
    bf16* Q2   = (bf16*)P1;
    bf16* SRC  = (bf16*)P2;
    bf16* CQ   = (bf16*)P3;
    bf16* CK   = (bf16*)P1;
    bf16* CV   = (bf16*)P0;
    bf16* U    = (bf16*)P2;
    bf16* UPb  = (bf16*)P0;
    bf16* GT   = (bf16*)P1;
    float* T3  = (float*)P2;         // 16 MiB: P2..P3
    bf16* Hb   = (bf16*)P4;
    bf16* Vtg  = (bf16*)P4;          // V-transpose scratch (8 MiB, dead before Hb)
    bf16* ACT  = (bf16*)P0;          // 16 MiB chunk: P0..P1
    bf16* X    = (bf16*)d_out;
    bf16* T2   = (bf16*)d_out;

    float* F    = (float*)SM;
    int* validP = (int*)(SM + 32 * 1024);
    int* validS = (int*)(SM + 48 * 1024);
    float* vrP  = (float*)(SM + 64 * 1024);
    float* vrS  = (float*)(SM + 64 * 1024 + 256);
    int* flags  = (int*)(SM + 64 * 1024 + 512);

    // 0) dtype probe on tokens
    probe_kernel<<<1, 256, 0, stream>>>(d_in[0], flags);

    // 0b) convert all float tensors to bf16 arena
    struct CvtJob { const void* src; bf16* dst; int n; };
    const CvtJob jobs[23] = {
        {d_in[0],  aTok,  4194304}, {d_in[1],  aSeq,  4194304}, {d_in[2],  aMod,  4096},
        {d_in[3],  aANW,  1024},    {d_in[4],  aQKVW, 3145728}, {d_in[5],  aQKVB, 3072},
        {d_in[6],  aOutW, 1048576}, {d_in[7],  aOutB, 1024},    {d_in[8],  aFilmW,2097152},
        {d_in[9],  aFilmB,2048},    {d_in[10], aSqN,  1024},    {d_in[11], aSN,   1024},
        {d_in[12], aMIW,  3145728}, {d_in[13], aMIB,  3072},    {d_in[14], aMOW,  1048576},
        {d_in[15], aMOB,  1024},    {d_in[16], aGW,   2097152}, {d_in[17], aGB,   1024},
        {d_in[18], aFNW,  1024},    {d_in[19], aGUW,  8388608}, {d_in[20], aGUB,  8192},
        {d_in[21], aDW,   4194304}, {d_in[22], aDB,   1024},
    };
    for (int j = 0; j < 23; ++j) {
        int blocks = (jobs[j].n + 2047) / 2048;
        cvt_kernel<<<blocks, 256, 0, stream>>>(jobs[j].src, jobs[j].dst, jobs[j].n, flags);
    }

    // 1) FiLM + masks
    film_kernel<<<32, 256, 0, stream>>>(aMod, aFilmW, aFilmB, F);
    mask_kernel<<<BB, 256, 0, stream>>>(d_in[23], validP, vrP);
    mask_kernel<<<BB, 256, 0, stream>>>(d_in[24], validS, vrS);

    // 2) X = rmsnorm(tokens)*film_scale + film_shift   (X in d_out)
    rmsnorm_kernel<bf16, 1><<<M, 256, 0, stream>>>(aTok, aANW, X, F);

    // 3) QKV = X @ qkv_w.T + qkv_b
    gemm128_kernel<0, false><<<dim3(24, 32), 256, 0, stream>>>(
        X, aQKVW, 1024, aQKVB, QKV, nullptr, nullptr, 1024, 3072);

    // 4) RoPE in-place on q,k
    rope_kernel<<<M, 256, 0, stream>>>(QKV);

    // 5) Self-attention (MFMA): V transpose into P4, then flash kernel -> A
    vtrans_kernel<<<dim3(16, 16, 4), 256, 0, stream>>>(QKV + 2048, 3072, Vtg);
    attn_mfma_kernel<<<dim3(16, 16, 4), 256, 0, stream>>>(QKV, QKV + 1024, 3072, Vtg, validP, A);

    // 6) T2 = tokens + A @ out_w.T + out_b   (into d_out; X dead)
    gemm128_kernel<1, false><<<dim3(8, 32), 256, 0, stream>>>(
        A, aOutW, 1024, aOutB, T2, aTok, nullptr, 1024, 1024);

    // 7/8) norms for cross-attn
    rmsnorm_kernel<bf16, 0><<<M, 256, 0, stream>>>(T2, aSqN, Q2, nullptr);
    rmsnorm_kernel<bf16, 0><<<M, 256, 0, stream>>>(aSeq, aSN, SRC, nullptr);

    // 9-11) cross projections (CQ first: CK overwrites Q2's panel)
    gemm128_kernel<0, false><<<dim3(8, 32), 256, 0, stream>>>(
        Q2, aMIW, 1024, aMIB, CQ, nullptr, nullptr, 1024, 1024);
    gemm128_kernel<0, false><<<dim3(8, 32), 256, 0, stream>>>(
        SRC, aMIW + 1048576, 1024, aMIB + 1024, CK, nullptr, nullptr, 1024, 1024);
    gemm128_kernel<0, false><<<dim3(8, 32), 256, 0, stream>>>(
        SRC, aMIW + 2097152, 1024, aMIB + 2048, CV, nullptr, nullptr, 1024, 1024);

    // 12) cross attention (MFMA) -> U
    vtrans_kernel<<<dim3(16, 16, 4), 256, 0, stream>>>(CV, 1024, Vtg);
    attn_mfma_kernel<<<dim3(16, 16, 4), 256, 0, stream>>>(CQ, CK, 1024, Vtg, validS, U);

    // 13) UPb = (U @ mha_out_w.T + b) * valid_rows
    gemm128_kernel<0, true><<<dim3(8, 32), 256, 0, stream>>>(
        U, aMOW, 1024, aMOB, UPb, nullptr, vrS, 1024, 1024);

    // 14) GT = sigmoid(T2@Wg[:, :1024].T + UPb@Wg[:, 1024:].T + b)
    gate128_kernel<<<dim3(8, 32), 256, 0, stream>>>(T2, UPb, aGW, aGB, GT);

    // 15) T3 = T2 + GT*UPb  (f32 into P2..P3)
    gating_kernel<<<(M * 1024) / 256, 256, 0, stream>>>(T2, GT, UPb, T3);

    // 16) Hb = rmsnorm(T3)  (into P4; Vtg dead)
    rmsnorm_kernel<float, 0><<<M, 256, 0, stream>>>(T3, aFNW, Hb, nullptr);

    // 17/18) FFN in two 2048-row chunks; final store dtype per flags
    for (int c = 0; c < 2; ++c) {
        const int row0 = c * 2048;
        gu128_kernel<<<dim3(64, 16), 256, 0, stream>>>(Hb + (size_t)row0 * 1024, aGUW, aGUB, ACT);
        down128_kernel<<<dim3(8, 16), 256, 0, stream>>>(ACT, aDW, aDB, d_out, T3, flags, row0);
    }
}

// Round 7
// 957.761 us; speedup vs baseline: 10.1055x; 1.1799x over previous
//
#include <hip/hip_runtime.h>
#include <hip/hip_bf16.h>
#include <math.h>

// Problem constants (B,S,L,D,H fixed by the reference)
#define BB 4
#define SS 1024
#define DD 1024
#define NH 16
#define HD 64

using bf16 = __hip_bfloat16;
typedef __bf16 bf16x8 __attribute__((ext_vector_type(8)));
typedef float f32x4 __attribute__((ext_vector_type(4)));

#define AS3(p) ((__attribute__((address_space(3))) void*)(p))
#define AS1(p) ((const __attribute__((address_space(1))) void*)(p))

// ---------------------------------------------------------------------------
// 128-tile GEMM machinery. Staging: global_load_lds width=16. LDS layout per
// 16-row group (1KB): [quad][l15][8] — identical to the load instruction's
// lane order AND the MFMA A/B fragment layout (no repack, 2-way max conflict).
// All K-loops are double-buffered: ds_read(cur) -> stage(nxt) -> MFMA -> 1
// barrier. The pre-barrier vmcnt drain then waits on loads that had the whole
// MFMA block to complete (critical at 1 block/CU).
// ---------------------------------------------------------------------------
__device__ __forceinline__ void stage128(const bf16* __restrict__ g, int ld,
                                         int row0, int k0, __bf16* lds,
                                         int wave, int lane)
{
    const int l15 = lane & 15, q = lane >> 4;
#pragma unroll
    for (int j = 0; j < 2; ++j) {
        int grp = wave * 2 + j;
        const bf16* gp = g + (size_t)(row0 + grp * 16 + l15) * ld + k0 + q * 8;
        __builtin_amdgcn_global_load_lds(AS1(gp), AS3((char*)lds + grp * 1024), 16, 0, 0);
    }
}

__device__ __forceinline__ void stage64(const bf16* __restrict__ g, int ld,
                                        int row0, int k0, __bf16* lds,
                                        int wave, int lane)
{
    const int l15 = lane & 15, q = lane >> 4;
    const bf16* gp = g + (size_t)(row0 + wave * 16 + l15) * ld + k0 + q * 8;
    __builtin_amdgcn_global_load_lds(AS1(gp), AS3((char*)lds + wave * 1024), 16, 0, 0);
}

__device__ __forceinline__ bf16x8 ldsfrag(const __bf16* lds, int grp, int quad, int l15)
{
    return *(const bf16x8*)((const char*)lds + grp * 1024 + quad * 256 + l15 * 16);
}

// ---------------------------------------------------------------------------
// Generic 128x128 GEMM: C[m,n] = A[m,:] . W[n,:] + bias[n] (+ epilogue).
// RES: 0 none, 1 bf16. SCALE: *scaleb[m0>>10] (tiles never cross batch).
// ---------------------------------------------------------------------------
template<int RES, bool SCALE>
__global__ __launch_bounds__(256)
void gemm128_kernel(const bf16* __restrict__ A, const bf16* __restrict__ W, int ldw,
                    const bf16* __restrict__ bias, bf16* __restrict__ Cout,
                    const bf16* __restrict__ Res, const float* __restrict__ scaleb,
                    int K, int ldc)
{
    __shared__ __bf16 As[2][4096], Bs[2][4096];
    const int wave = threadIdx.x >> 6, lane = threadIdx.x & 63;
    const int quad = lane >> 4, l15 = lane & 15;
    const int n0 = blockIdx.x * 128, m0 = blockIdx.y * 128;
    const int mg0 = (wave >> 1) * 4, ng0 = (wave & 1) * 4;

    stage128(A, K, m0, 0, As[0], wave, lane);
    stage128(W, ldw, n0, 0, Bs[0], wave, lane);

    f32x4 acc[4][4] = {};
    const int steps = K >> 5;
    for (int s = 0; s < steps; ++s) {
        __syncthreads();                       // buf[cur] loads landed (vmcnt drain)
        const int cur = s & 1, nxt = cur ^ 1;
        bf16x8 af[4], bfv[4];
#pragma unroll
        for (int i = 0; i < 4; ++i) af[i] = ldsfrag(As[cur], mg0 + i, quad, l15);
#pragma unroll
        for (int j = 0; j < 4; ++j) bfv[j] = ldsfrag(Bs[cur], ng0 + j, quad, l15);
        if (s + 1 < steps) {
            stage128(A, K, m0, (s + 1) * 32, As[nxt], wave, lane);
            stage128(W, ldw, n0, (s + 1) * 32, Bs[nxt], wave, lane);
        }
#pragma unroll
        for (int i = 0; i < 4; ++i)
#pragma unroll
            for (int j = 0; j < 4; ++j)
                acc[i][j] = __builtin_amdgcn_mfma_f32_16x16x32_bf16(af[i], bfv[j], acc[i][j], 0, 0, 0);
    }

    const float scl = SCALE ? scaleb[m0 >> 10] : 1.f;
#pragma unroll
    for (int i = 0; i < 4; ++i)
#pragma unroll
        for (int j = 0; j < 4; ++j) {
            const int col = n0 + (ng0 + j) * 16 + l15;
            const float bs = (float)bias[col];
#pragma unroll
            for (int r = 0; r < 4; ++r) {
                int row = m0 + (mg0 + i) * 16 + quad * 4 + r;
                float v = acc[i][j][r] + bs;
                if (SCALE) v *= scl;
                size_t off = (size_t)row * ldc + col;
                if (RES == 1) v += (float)Res[off];
                Cout[off] = __float2bfloat16(v);
            }
        }
}

// ---------------------------------------------------------------------------
// Gate GEMM (128-tile, dbuf): GT = sigmoid(A1@Wg[:, :1024].T + A2@Wg[:, 1024:].T + b)
// K phased over 64 steps: s<32 -> A1 / W cols 0..1023; s>=32 -> A2 / cols 1024+.
// ---------------------------------------------------------------------------
__global__ __launch_bounds__(256)
void gate128_kernel(const bf16* __restrict__ A1, const bf16* __restrict__ A2,
                    const bf16* __restrict__ Wg, const bf16* __restrict__ bias,
                    bf16* __restrict__ GT)
{
    __shared__ __bf16 As[2][4096], Bs[2][4096];
    const int wave = threadIdx.x >> 6, lane = threadIdx.x & 63;
    const int quad = lane >> 4, l15 = lane & 15;
    const int n0 = blockIdx.x * 128, m0 = blockIdx.y * 128;
    const int mg0 = (wave >> 1) * 4, ng0 = (wave & 1) * 4;

    stage128(A1, 1024, m0, 0, As[0], wave, lane);
    stage128(Wg, 2048, n0, 0, Bs[0], wave, lane);

    f32x4 acc[4][4] = {};
    for (int s = 0; s < 64; ++s) {
        __syncthreads();
        const int cur = s & 1, nxt = cur ^ 1;
        bf16x8 af[4], bfv[4];
#pragma unroll
        for (int i = 0; i < 4; ++i) af[i] = ldsfrag(As[cur], mg0 + i, quad, l15);
#pragma unroll
        for (int j = 0; j < 4; ++j) bfv[j] = ldsfrag(Bs[cur], ng0 + j, quad, l15);
        if (s + 1 < 64) {
            const bf16* Asrc = (s + 1 < 32) ? A1 : A2;
            stage128(Asrc, 1024, m0, ((s + 1) & 31) * 32, As[nxt], wave, lane);
            stage128(Wg, 2048, n0, (s + 1) * 32, Bs[nxt], wave, lane);
        }
#pragma unroll
        for (int i = 0; i < 4; ++i)
#pragma unroll
            for (int j = 0; j < 4; ++j)
                acc[i][j] = __builtin_amdgcn_mfma_f32_16x16x32_bf16(af[i], bfv[j], acc[i][j], 0, 0, 0);
    }

#pragma unroll
    for (int i = 0; i < 4; ++i)
#pragma unroll
        for (int j = 0; j < 4; ++j) {
            const int col = n0 + (ng0 + j) * 16 + l15;
            const float bs = (float)bias[col];
#pragma unroll
            for (int r = 0; r < 4; ++r) {
                int row = m0 + (mg0 + i) * 16 + quad * 4 + r;
                float v = fminf(fmaxf(acc[i][j][r] + bs, -60.f), 60.f);
                GT[(size_t)row * 1024 + col] = __float2bfloat16(1.f / (1.f + __expf(-v)));
            }
        }
}

// ---------------------------------------------------------------------------
// Fused SwiGLU GEMM (128 rows x 64 cols-per-half, dbuf), full M:
// ACT[m,n] = silu(Hb@gu_w[n].T+b[n]) * (Hb@gu_w[4096+n].T+b[4096+n])
// ---------------------------------------------------------------------------
__global__ __launch_bounds__(256)
void gu128_kernel(const bf16* __restrict__ Hb, const bf16* __restrict__ Wgu,
                  const bf16* __restrict__ bgu, bf16* __restrict__ ACT)
{
    __shared__ __bf16 As[2][4096], Bg[2][2048], Bv[2][2048];
    const int wave = threadIdx.x >> 6, lane = threadIdx.x & 63;
    const int quad = lane >> 4, l15 = lane & 15;
    const int n0 = blockIdx.x * 64, m0 = blockIdx.y * 128;
    const int mg0 = (wave >> 1) * 4, ng0 = (wave & 1) * 2;
    const bf16* WguV = Wgu + (size_t)4096 * 1024;

    stage128(Hb, 1024, m0, 0, As[0], wave, lane);
    stage64(Wgu,  1024, n0, 0, Bg[0], wave, lane);
    stage64(WguV, 1024, n0, 0, Bv[0], wave, lane);

    f32x4 ag[4][2] = {}, av[4][2] = {};
    for (int s = 0; s < 32; ++s) {
        __syncthreads();
        const int cur = s & 1, nxt = cur ^ 1;
        bf16x8 af[4], bgf[2], bvf[2];
#pragma unroll
        for (int i = 0; i < 4; ++i) af[i] = ldsfrag(As[cur], mg0 + i, quad, l15);
#pragma unroll
        for (int j = 0; j < 2; ++j) {
            bgf[j] = ldsfrag(Bg[cur], ng0 + j, quad, l15);
            bvf[j] = ldsfrag(Bv[cur], ng0 + j, quad, l15);
        }
        if (s + 1 < 32) {
            stage128(Hb, 1024, m0, (s + 1) * 32, As[nxt], wave, lane);
            stage64(Wgu,  1024, n0, (s + 1) * 32, Bg[nxt], wave, lane);
            stage64(WguV, 1024, n0, (s + 1) * 32, Bv[nxt], wave, lane);
        }
#pragma unroll
        for (int i = 0; i < 4; ++i)
#pragma unroll
            for (int j = 0; j < 2; ++j) {
                ag[i][j] = __builtin_amdgcn_mfma_f32_16x16x32_bf16(af[i], bgf[j], ag[i][j], 0, 0, 0);
                av[i][j] = __builtin_amdgcn_mfma_f32_16x16x32_bf16(af[i], bvf[j], av[i][j], 0, 0, 0);
            }
    }

#pragma unroll
    for (int i = 0; i < 4; ++i)
#pragma unroll
        for (int j = 0; j < 2; ++j) {
            const int col = n0 + (ng0 + j) * 16 + l15;
            const float bg = (float)bgu[col];
            const float bv = (float)bgu[4096 + col];
#pragma unroll
            for (int r = 0; r < 4; ++r) {
                int row = m0 + (mg0 + i) * 16 + quad * 4 + r;
                float g = fminf(fmaxf(ag[i][j][r] + bg, -60.f), 60.f);
                float v = av[i][j][r] + bv;
                float sg = g / (1.f + __expf(-g));
                ACT[(size_t)row * 4096 + col] = __float2bfloat16(sg * v);
            }
        }
}

// ---------------------------------------------------------------------------
// Down-proj GEMM (128-tile, dbuf), full M: out = ACT@W.T + b + T3(bf16 res),
// stored fp32 or bf16 per flags[0].
// ---------------------------------------------------------------------------
__global__ __launch_bounds__(256)
void down128_kernel(const bf16* __restrict__ ACT, const bf16* __restrict__ W,
                    const bf16* __restrict__ bias, void* __restrict__ out,
                    const bf16* __restrict__ T3, const int* __restrict__ flags)
{
    __shared__ __bf16 As[2][4096], Bs[2][4096];
    const int wave = threadIdx.x >> 6, lane = threadIdx.x & 63;
    const int quad = lane >> 4, l15 = lane & 15;
    const int n0 = blockIdx.x * 128, m0 = blockIdx.y * 128;
    const int mg0 = (wave >> 1) * 4, ng0 = (wave & 1) * 4;

    stage128(ACT, 4096, m0, 0, As[0], wave, lane);
    stage128(W,   4096, n0, 0, Bs[0], wave, lane);

    f32x4 acc[4][4] = {};
    for (int s = 0; s < 128; ++s) {
        __syncthreads();
        const int cur = s & 1, nxt = cur ^ 1;
        bf16x8 af[4], bfv[4];
#pragma unroll
        for (int i = 0; i < 4; ++i) af[i] = ldsfrag(As[cur], mg0 + i, quad, l15);
#pragma unroll
        for (int j = 0; j < 4; ++j) bfv[j] = ldsfrag(Bs[cur], ng0 + j, quad, l15);
        if (s + 1 < 128) {
            stage128(ACT, 4096, m0, (s + 1) * 32, As[nxt], wave, lane);
            stage128(W,   4096, n0, (s + 1) * 32, Bs[nxt], wave, lane);
        }
#pragma unroll
        for (int i = 0; i < 4; ++i)
#pragma unroll
            for (int j = 0; j < 4; ++j)
                acc[i][j] = __builtin_amdgcn_mfma_f32_16x16x32_bf16(af[i], bfv[j], acc[i][j], 0, 0, 0);
    }

    const int f32out = flags[0];
#pragma unroll
    for (int i = 0; i < 4; ++i)
#pragma unroll
        for (int j = 0; j < 4; ++j) {
            const int col = n0 + (ng0 + j) * 16 + l15;
            const float bs = (float)bias[col];
#pragma unroll
            for (int r = 0; r < 4; ++r) {
                size_t row = (size_t)m0 + (mg0 + i) * 16 + quad * 4 + r;
                size_t off = row * 1024 + col;
                float v = acc[i][j][r] + bs + (float)T3[off];
                if (f32out) ((float*)out)[off] = v;
                else        ((bf16*)out)[off] = __float2bfloat16(v);
            }
        }
}

// ---------------------------------------------------------------------------
// Dtype probe: flags[0] = 1 if the float buffers are fp32, 0 if bf16.
// ---------------------------------------------------------------------------
__global__ __launch_bounds__(256)
void probe_kernel(const void* __restrict__ tokens, int* __restrict__ flags)
{
    const unsigned short* u = (const unsigned short*)tokens;
    int t = threadIdx.x, bad = 0;
    for (int i = t; i < 8192; i += 256) {
        int e = (u[i] >> 7) & 0xFF;
        if (e >= 0xC5) bad++;
    }
    __shared__ int red[256];
    red[t] = bad; __syncthreads();
    for (int s = 128; s > 0; s >>= 1) { if (t < s) red[t] += red[t + s]; __syncthreads(); }
    if (t == 0) flags[0] = (red[0] > 16) ? 1 : 0;
}

// ---------------------------------------------------------------------------
// Batched convert: all 23 float tensors in ONE launch. Job table by value.
// ---------------------------------------------------------------------------
struct CvtJobs {
    const void* src[23];
    bf16* dst[23];
    int n[23];
    int blk0[24];
};

__global__ __launch_bounds__(256)
void cvt_all_kernel(CvtJobs J, const int* __restrict__ flags)
{
    int b = blockIdx.x, j = 0;
    while (b >= J.blk0[j + 1]) ++j;
    int i0 = (b - J.blk0[j]) * 2048 + threadIdx.x * 8;
    if (i0 >= J.n[j]) return;
    bf16* dst = J.dst[j];
    if (flags[0]) {
        const float* s = (const float*)J.src[j];
#pragma unroll
        for (int e = 0; e < 8; ++e) dst[i0 + e] = __float2bfloat16(s[i0 + e]);
    } else {
        *(bf16x8*)(dst + i0) = *(const bf16x8*)((const bf16*)J.src[j] + i0);
    }
}

// ---------------------------------------------------------------------------
// FiLM projection
// ---------------------------------------------------------------------------
__global__ __launch_bounds__(256)
void film_kernel(const bf16* __restrict__ mod, const bf16* __restrict__ fw,
                 const bf16* __restrict__ fb, float* __restrict__ F)
{
    int o = blockIdx.x * 256 + threadIdx.x;    // 0..8191
    int b = o >> 11, c = o & 2047;
    const bf16x8* m = (const bf16x8*)(mod + b * DD);
    const bf16x8* w = (const bf16x8*)(fw + (size_t)c * DD);
    float s = (float)fb[c];
    for (int j = 0; j < DD / 8; ++j) {
        bf16x8 mv = m[j], wv = w[j];
#pragma unroll
        for (int e = 0; e < 8; ++e) s += (float)mv[e] * (float)wv[e];
    }
    if (c < 1024) s = 1.f + 0.1f * tanhf(s);
    F[o] = s;
}

// ---------------------------------------------------------------------------
// RMSNorm (optionally + FiLM). One block per row of 1024.
// ---------------------------------------------------------------------------
template<typename TIN, int FILM>
__global__ __launch_bounds__(256)
void rmsnorm_kernel(const TIN* __restrict__ in, const bf16* __restrict__ w,
                    bf16* __restrict__ out, const float* __restrict__ F)
{
    int row = blockIdx.x, t = threadIdx.x, b = row >> 10;
    const TIN* x = in + (size_t)row * DD;
    float v[4];
#pragma unroll
    for (int i = 0; i < 4; ++i) v[i] = (float)x[t * 4 + i];
    float ss = v[0]*v[0] + v[1]*v[1] + v[2]*v[2] + v[3]*v[3];
    __shared__ float red[256];
    red[t] = ss; __syncthreads();
    for (int s = 128; s > 0; s >>= 1) { if (t < s) red[t] += red[t + s]; __syncthreads(); }
    float rn = rsqrtf(red[0] * (1.f / DD) + 1e-6f);
#pragma unroll
    for (int i = 0; i < 4; ++i) {
        int d = t * 4 + i;
        float y = v[i] * rn * (float)w[d];
        if (FILM) y = y * F[b * 2048 + d] + F[b * 2048 + 1024 + d];
        out[(size_t)row * DD + d] = __float2bfloat16(y);
    }
}

// ---------------------------------------------------------------------------
// Mask preprocessing with in-kernel int32-vs-int8 detection.
// ---------------------------------------------------------------------------
__global__ __launch_bounds__(256)
void mask_kernel(const void* __restrict__ mask, int* __restrict__ valid,
                 float* __restrict__ vr)
{
    int b = blockIdx.x, t = threadIdx.x;
    const unsigned* mi = (const unsigned*)mask;
    const unsigned char* mb = (const unsigned char*)mask;
    __shared__ int red[256];

    int viol = 0;
    for (int i = t; i < 1024; i += 256) if (mi[i] > 1u) viol++;
    red[t] = viol; __syncthreads();
    for (int s = 128; s > 0; s >>= 1) { if (t < s) red[t] += red[t + s]; __syncthreads(); }
    int isByte = (red[0] > 0);
    __syncthreads();

    int z = 0;
    for (int i = t; i < SS; i += 256) {
        int mv = isByte ? (int)mb[b * SS + i] : (int)mi[b * SS + i];
        z += (mv == 0);
    }
    red[t] = z; __syncthreads();
    for (int s = 128; s > 0; s >>= 1) { if (t < s) red[t] += red[t + s]; __syncthreads(); }
    int nvalid = red[0];
    int allpad = (nvalid == 0);
    for (int i = t; i < SS; i += 256) {
        int mv = isByte ? (int)mb[b * SS + i] : (int)mi[b * SS + i];
        valid[b * SS + i] = allpad ? 1 : (mv ? 0 : 1);
    }
    if (t == 0) vr[b] = (nvalid > 0) ? 1.f : 0.f;
}

// ---------------------------------------------------------------------------
// RoPE in-place on q,k sections of the (4096, 3072) interleaved QKV buffer.
// ---------------------------------------------------------------------------
__global__ __launch_bounds__(256)
void rope_kernel(bf16* __restrict__ qkv)
{
    int row = blockIdx.x;
    int s = row & (SS - 1);
    for (int j = threadIdx.x; j < 1024; j += 256) {
        int sec = j >> 9;
        int p = j & 511;
        int i = p & 31;
        int col = sec * DD + p * 2;
        float fi = __expf(-(float)(2 * i) * 0.14391157f);   // ln(10000)/64
        float ang = (float)s * fi;
        float sn, cs; sincosf(ang, &sn, &cs);
        size_t base = (size_t)row * (3 * DD) + col;
        float e = (float)qkv[base], o = (float)qkv[base + 1];
        qkv[base]     = __float2bfloat16(e * cs - o * sn);
        qkv[base + 1] = __float2bfloat16(e * sn + o * cs);
    }
}

// ---------------------------------------------------------------------------
// V transpose: vtg[(b*16+h)*64 + d][k] = V[b*1024+k][h*64+d].
// ---------------------------------------------------------------------------
__global__ __launch_bounds__(256)
void vtrans_kernel(const bf16* __restrict__ vsrc, int ld, bf16* __restrict__ vtg)
{
    __shared__ __bf16 tile[64][65];
    const int t = threadIdx.x;
    const int k0 = blockIdx.x * 64;
    const int h = blockIdx.y, b = blockIdx.z;
#pragma unroll
    for (int j = 0; j < 2; ++j) {
        int lin = j * 256 + t;
        int r = lin >> 3, c8 = (lin & 7) * 8;
        bf16x8 v = *(const bf16x8*)(vsrc + ((size_t)b * 1024 + k0 + r) * ld + h * 64 + c8);
#pragma unroll
        for (int e = 0; e < 8; ++e) tile[r][c8 + e] = v[e];
    }
    __syncthreads();
#pragma unroll
    for (int j = 0; j < 2; ++j) {
        int lin = j * 256 + t;
        int d = lin >> 3, k8 = (lin & 7) * 8;
        __bf16 o[8];
#pragma unroll
        for (int e = 0; e < 8; ++e) o[e] = tile[k8 + e][d];
        *(bf16x8*)(vtg + ((size_t)(b * 16 + h) * 64 + d) * 1024 + k0 + k8) = *(bf16x8*)o;
    }
}

// ---------------------------------------------------------------------------
// Flash-style MFMA attention (unchanged).
// ---------------------------------------------------------------------------
__global__ __launch_bounds__(256)
void attn_mfma_kernel(const bf16* __restrict__ qp, const bf16* __restrict__ kp,
                      int ld, const bf16* __restrict__ vtg,
                      const int* __restrict__ valid, bf16* __restrict__ out)
{
    __shared__ __bf16 Kl[128][72];
    __shared__ __bf16 Vl[64][136];
    __shared__ __bf16 Pl[4][16][136];
    __shared__ float biasl[1024];

    const int t = threadIdx.x;
    const int wave = t >> 6, lane = t & 63, quad = lane >> 4, l15 = lane & 15;
    const int q0 = blockIdx.x * 64;
    const int h = blockIdx.y, b = blockIdx.z;

    for (int i = t; i < 1024; i += 256)
        biasl[i] = valid[b * 1024 + i] ? 0.f : -1e30f;

    const size_t qrow = (size_t)b * 1024 + q0 + wave * 16 + l15;
    const bf16x8 qf0 = *(const bf16x8*)(qp + qrow * ld + h * 64 + quad * 8);
    const bf16x8 qf1 = *(const bf16x8*)(qp + qrow * ld + h * 64 + 32 + quad * 8);

    f32x4 O[4] = {{0,0,0,0},{0,0,0,0},{0,0,0,0},{0,0,0,0}};
    float mrow[4] = {-1e30f, -1e30f, -1e30f, -1e30f};
    float lrow[4] = {0.f, 0.f, 0.f, 0.f};

    for (int ic = 0; ic < 8; ++ic) {
        const int k0 = ic * 128;
        __syncthreads();
#pragma unroll
        for (int j = 0; j < 4; ++j) {
            int lin = j * 256 + t;
            int r = lin >> 3, c8 = (lin & 7) * 8;
            *(bf16x8*)&Kl[r][c8] =
                *(const bf16x8*)(kp + ((size_t)b * 1024 + k0 + r) * ld + h * 64 + c8);
            int d = lin >> 4, s8 = (lin & 15) * 8;
            *(bf16x8*)&Vl[d][s8] =
                *(const bf16x8*)(vtg + ((size_t)(b * 16 + h) * 64 + d) * 1024 + k0 + s8);
        }
        __syncthreads();

        float sreg[8][4];
#pragma unroll
        for (int f = 0; f < 8; ++f) {
            bf16x8 kb0 = *(const bf16x8*)&Kl[f * 16 + l15][quad * 8];
            bf16x8 kb1 = *(const bf16x8*)&Kl[f * 16 + l15][32 + quad * 8];
            f32x4 s = {0, 0, 0, 0};
            s = __builtin_amdgcn_mfma_f32_16x16x32_bf16(qf0, kb0, s, 0, 0, 0);
            s = __builtin_amdgcn_mfma_f32_16x16x32_bf16(qf1, kb1, s, 0, 0, 0);
            float bfr = biasl[k0 + f * 16 + l15];
#pragma unroll
            for (int i = 0; i < 4; ++i) sreg[f][i] = s[i] * 0.125f + bfr;
        }

        float mloc[4] = {-1e30f, -1e30f, -1e30f, -1e30f};
#pragma unroll
        for (int f = 0; f < 8; ++f)
#pragma unroll
            for (int i = 0; i < 4; ++i) mloc[i] = fmaxf(mloc[i], sreg[f][i]);
#pragma unroll
        for (int off = 1; off < 16; off <<= 1)
#pragma unroll
            for (int i = 0; i < 4; ++i)
                mloc[i] = fmaxf(mloc[i], __shfl_xor(mloc[i], off));
        float alpha[4];
#pragma unroll
        for (int i = 0; i < 4; ++i) {
            float mn = fmaxf(mrow[i], mloc[i]);
            alpha[i] = __expf(mrow[i] - mn);
            mrow[i] = mn;
            lrow[i] *= alpha[i];
        }
#pragma unroll
        for (int dt = 0; dt < 4; ++dt)
#pragma unroll
            for (int i = 0; i < 4; ++i) O[dt][i] *= alpha[i];

        float lloc[4] = {0.f, 0.f, 0.f, 0.f};
#pragma unroll
        for (int f = 0; f < 8; ++f)
#pragma unroll
            for (int i = 0; i < 4; ++i) {
                float p = __expf(sreg[f][i] - mrow[i]);
                lloc[i] += p;
                Pl[wave][quad * 4 + i][f * 16 + l15] = (__bf16)p;
            }
#pragma unroll
        for (int off = 1; off < 16; off <<= 1)
#pragma unroll
            for (int i = 0; i < 4; ++i) lloc[i] += __shfl_xor(lloc[i], off);
#pragma unroll
        for (int i = 0; i < 4; ++i) lrow[i] += lloc[i];

        __syncthreads();

#pragma unroll
        for (int kc = 0; kc < 4; ++kc) {
            bf16x8 pa = *(const bf16x8*)&Pl[wave][l15][kc * 32 + quad * 8];
#pragma unroll
            for (int dt = 0; dt < 4; ++dt) {
                bf16x8 vb = *(const bf16x8*)&Vl[dt * 16 + l15][kc * 32 + quad * 8];
                O[dt] = __builtin_amdgcn_mfma_f32_16x16x32_bf16(pa, vb, O[dt], 0, 0, 0);
            }
        }
    }

#pragma unroll
    for (int i = 0; i < 4; ++i) {
        float inv = 1.f / lrow[i];
        size_t orow = (size_t)b * 1024 + q0 + wave * 16 + quad * 4 + i;
#pragma unroll
        for (int dt = 0; dt < 4; ++dt)
            out[orow * 1024 + h * 64 + dt * 16 + l15] = __float2bfloat16(O[dt][i] * inv);
    }
}

// ---------------------------------------------------------------------------
// T3(bf16) = T2 + gate * update
// ---------------------------------------------------------------------------
__global__ __launch_bounds__(256)
void gating_kernel(const bf16* __restrict__ T2, const bf16* __restrict__ GT,
                   const bf16* __restrict__ UPb, bf16* __restrict__ T3)
{
    size_t idx = (size_t)blockIdx.x * 256 + threadIdx.x;
    T3[idx] = __float2bfloat16((float)T2[idx] + (float)GT[idx] * (float)UPb[idx]);
}

// ---------------------------------------------------------------------------
extern "C" void kernel_launch(void* const* d_in, const int* in_sizes, int n_in,
                              void* d_out, int out_size, void* d_ws, size_t ws_size,
                              hipStream_t stream)
{
    const int M = BB * SS;            // 4096 rows
    const size_t MiB = 1 << 20;

    char* ws = (char*)d_ws;

    // ---- bf16 arena for converted inputs (~64.1 MB) ----
    size_t off = 0;
    auto arena = [&](size_t n) { bf16* p = (bf16*)(ws + off); off += ((n * 2 + 255) & ~(size_t)255); return p; };
    bf16* aTok  = arena(4194304);
    bf16* aSeq  = arena(4194304);
    bf16* aMod  = arena(4096);
    bf16* aANW  = arena(1024);
    bf16* aQKVW = arena(3145728);
    bf16* aQKVB = arena(3072);
    bf16* aOutW = arena(1048576);
    bf16* aOutB = arena(1024);
    bf16* aFilmW= arena(2097152);
    bf16* aFilmB= arena(2048);
    bf16* aSqN  = arena(1024);
    bf16* aSN   = arena(1024);
    bf16* aMIW  = arena(3145728);
    bf16* aMIB  = arena(3072);
    bf16* aMOW  = arena(1048576);
    bf16* aMOB  = arena(1024);
    bf16* aGW   = arena(2097152);
    bf16* aGB   = arena(1024);
    bf16* aFNW  = arena(1024);
    bf16* aGUW  = arena(8388608);
    bf16* aGUB  = arena(8192);
    bf16* aDW   = arena(4194304);
    bf16* aDB   = arena(1024);

    // ---- pipeline panels (5 x 8 MiB) + smalls ----
    // P0: A[5-6]  CV[11-12]  UPb[13-15]  \
    // P1: QKV...  Q2[7-9]   CK[10-12] GT[14-15] | ACT (32 MiB) [17-18]
    // P2: ...QKV  SRC[8-11] U[12-13]   |
    // P3: ...QKV  CQ[9-12]             /
    // P4: Vtg(self)[5] Vtg(cross)[12]  T3 bf16 [15-18]
    // d_out: X[2-3] T2[6-15] Hb[16-17] final out[18]
    off = (off + MiB - 1) & ~(MiB - 1);
    char* P0 = ws + off;
    char* P1 = P0 + 8 * MiB;
    char* P2 = P0 + 16 * MiB;
    char* P3 = P0 + 24 * MiB;
    char* P4 = P0 + 32 * MiB;
    char* SM = P0 + 40 * MiB;

    bf16* QKV  = (bf16*)P1;
    bf16* A    = (bf16*)P0;
    bf16* Q2   = (bf16*)P1;
    bf16* SRC  = (bf16*)P2;
    bf16* CQ   = (bf16*)P3;
    bf16* CK   = (bf16*)P1;
    bf16* CV   = (bf16*)P0;
    bf16* U    = (bf16*)P2;
    bf16* UPb  = (bf16*)P0;
    bf16* GT   = (bf16*)P1;
    bf16* T3   = (bf16*)P4;
    bf16* Vtg  = (bf16*)P4;
    bf16* ACT  = (bf16*)P0;          // 32 MiB: P0..P3
    bf16* X    = (bf16*)d_out;
    bf16* T2   = (bf16*)d_out;
    bf16* Hb   = (bf16*)d_out;

    float* F    = (float*)SM;
    int* validP = (int*)(SM + 32 * 1024);
    int* validS = (int*)(SM + 48 * 1024);
    float* vrP  = (float*)(SM + 64 * 1024);
    float* vrS  = (float*)(SM + 64 * 1024 + 256);
    int* flags  = (int*)(SM + 64 * 1024 + 512);

    // 0) dtype probe on tokens
    probe_kernel<<<1, 256, 0, stream>>>(d_in[0], flags);

    // 0b) convert all 23 float tensors in one launch
    CvtJobs J;
    const void* srcs[23] = {d_in[0], d_in[1], d_in[2], d_in[3], d_in[4], d_in[5],
                            d_in[6], d_in[7], d_in[8], d_in[9], d_in[10], d_in[11],
                            d_in[12], d_in[13], d_in[14], d_in[15], d_in[16], d_in[17],
                            d_in[18], d_in[19], d_in[20], d_in[21], d_in[22]};
    bf16* dsts[23] = {aTok, aSeq, aMod, aANW, aQKVW, aQKVB, aOutW, aOutB, aFilmW,
                      aFilmB, aSqN, aSN, aMIW, aMIB, aMOW, aMOB, aGW, aGB, aFNW,
                      aGUW, aGUB, aDW, aDB};
    const int ns[23] = {4194304, 4194304, 4096, 1024, 3145728, 3072, 1048576, 1024,
                        2097152, 2048, 1024, 1024, 3145728, 3072, 1048576, 1024,
                        2097152, 1024, 1024, 8388608, 8192, 4194304, 1024};
    int acc_blk = 0;
    for (int j = 0; j < 23; ++j) {
        J.src[j] = srcs[j]; J.dst[j] = dsts[j]; J.n[j] = ns[j];
        J.blk0[j] = acc_blk;
        acc_blk += (ns[j] + 2047) / 2048;
    }
    J.blk0[23] = acc_blk;
    cvt_all_kernel<<<acc_blk, 256, 0, stream>>>(J, flags);

    // 1) FiLM + masks
    film_kernel<<<32, 256, 0, stream>>>(aMod, aFilmW, aFilmB, F);
    mask_kernel<<<BB, 256, 0, stream>>>(d_in[23], validP, vrP);
    mask_kernel<<<BB, 256, 0, stream>>>(d_in[24], validS, vrS);

    // 2) X = rmsnorm(tokens)*film_scale + film_shift   (X in d_out)
    rmsnorm_kernel<bf16, 1><<<M, 256, 0, stream>>>(aTok, aANW, X, F);

    // 3) QKV = X @ qkv_w.T + qkv_b
    gemm128_kernel<0, false><<<dim3(24, 32), 256, 0, stream>>>(
        X, aQKVW, 1024, aQKVB, QKV, nullptr, nullptr, 1024, 3072);

    // 4) RoPE in-place on q,k
    rope_kernel<<<M, 256, 0, stream>>>(QKV);

    // 5) Self-attention (MFMA): V transpose into P4, then flash kernel -> A
    vtrans_kernel<<<dim3(16, 16, 4), 256, 0, stream>>>(QKV + 2048, 3072, Vtg);
    attn_mfma_kernel<<<dim3(16, 16, 4), 256, 0, stream>>>(QKV, QKV + 1024, 3072, Vtg, validP, A);

    // 6) T2 = tokens + A @ out_w.T + out_b   (into d_out; X dead)
    gemm128_kernel<1, false><<<dim3(8, 32), 256, 0, stream>>>(
        A, aOutW, 1024, aOutB, T2, aTok, nullptr, 1024, 1024);

    // 7/8) norms for cross-attn
    rmsnorm_kernel<bf16, 0><<<M, 256, 0, stream>>>(T2, aSqN, Q2, nullptr);
    rmsnorm_kernel<bf16, 0><<<M, 256, 0, stream>>>(aSeq, aSN, SRC, nullptr);

    // 9-11) cross projections (CQ first: CK overwrites Q2's panel)
    gemm128_kernel<0, false><<<dim3(8, 32), 256, 0, stream>>>(
        Q2, aMIW, 1024, aMIB, CQ, nullptr, nullptr, 1024, 1024);
    gemm128_kernel<0, false><<<dim3(8, 32), 256, 0, stream>>>(
        SRC, aMIW + 1048576, 1024, aMIB + 1024, CK, nullptr, nullptr, 1024, 1024);
    gemm128_kernel<0, false><<<dim3(8, 32), 256, 0, stream>>>(
        SRC, aMIW + 2097152, 1024, aMIB + 2048, CV, nullptr, nullptr, 1024, 1024);

    // 12) cross attention (MFMA) -> U
    vtrans_kernel<<<dim3(16, 16, 4), 256, 0, stream>>>(CV, 1024, Vtg);
    attn_mfma_kernel<<<dim3(16, 16, 4), 256, 0, stream>>>(CQ, CK, 1024, Vtg, validS, U);

    // 13) UPb = (U @ mha_out_w.T + b) * valid_rows
    gemm128_kernel<0, true><<<dim3(8, 32), 256, 0, stream>>>(
        U, aMOW, 1024, aMOB, UPb, nullptr, vrS, 1024, 1024);

    // 14) GT = sigmoid(T2@Wg[:, :1024].T + UPb@Wg[:, 1024:].T + b)
    gate128_kernel<<<dim3(8, 32), 256, 0, stream>>>(T2, UPb, aGW, aGB, GT);

    // 15) T3 = T2 + GT*UPb  (bf16 into P4; Vtg dead)
    gating_kernel<<<(M * 1024) / 256, 256, 0, stream>>>(T2, GT, UPb, T3);

    // 16) Hb = rmsnorm(T3)  (into d_out; T2 dead)
    rmsnorm_kernel<bf16, 0><<<M, 256, 0, stream>>>(T3, aFNW, Hb, nullptr);

    // 17) ACT = SwiGLU(Hb @ gu_w.T + gu_b)  (full M, ACT in P0..P3)
    gu128_kernel<<<dim3(64, 32), 256, 0, stream>>>(Hb, aGUW, aGUB, ACT);

    // 18) d_out = T3 + ACT @ down_w.T + down_b  (full M; store dtype per flags)
    down128_kernel<<<dim3(8, 32), 256, 0, stream>>>(ACT, aDW, aDB, d_out, T3, flags);
}